// Round 2
// baseline (778.500 us; speedup 1.0000x reference)
//
#include <hip/hip_runtime.h>

#define NTOK 4096

typedef float f32x4 __attribute__((ext_vector_type(4)));
typedef short s16x8 __attribute__((ext_vector_type(8)));
typedef unsigned short u16x4 __attribute__((ext_vector_type(4)));
typedef unsigned short u16x8 __attribute__((ext_vector_type(8)));

__device__ __forceinline__ unsigned short fbf(float f) {
  unsigned int u = __float_as_uint(f);
  return (unsigned short)((u + 0x7FFFu + ((u >> 16) & 1u)) >> 16);
}
__device__ __forceinline__ float bf2f(unsigned short s) {
  return __uint_as_float(((unsigned int)s) << 16);
}
__device__ __forceinline__ float gelu_new_f(float x) {
  float inner = 0.7978845608028654f * (x + 0.044715f * x * x * x);
  return 0.5f * x * (1.0f + tanhf(inner));
}

// async global->LDS, 16B per lane. LDS dest = wave-uniform base + lane*16.
__device__ __forceinline__ void gl_lds16(const void* g, void* l) {
  __builtin_amdgcn_global_load_lds(
      (const __attribute__((address_space(1))) unsigned int*)g,
      (__attribute__((address_space(3))) unsigned int*)l, 16, 0, 0);
}

// -------------------- embedding gather (fp32 x) --------------------
__global__ void embed_kernel(const int* __restrict__ ids, const float* __restrict__ emb,
                             float* __restrict__ x) {
  int tok = blockIdx.x;
  int id = ids[tok];
  int t = threadIdx.x;
  *(float4*)(x + (size_t)tok * 512 + t * 4) = *(const float4*)(emb + (size_t)id * 512 + t * 4);
}

// -------------------- relative-position delta-bias table --------------------
__global__ void build_dbias_kernel(const float* __restrict__ rel_bias, float* __restrict__ dbias) {
  int d = blockIdx.x * 256 + threadIdx.x;
  if (d >= 4096) return;
  int rel = d - 2047;
  int bucket = (rel > 0) ? 16 : 0;
  int rp = rel < 0 ? -rel : rel;
  if (rp < 8) {
    bucket += rp;
  } else {
    float v = logf((float)rp / 8.0f) / logf(16.0f) * 8.0f;
    int rl = 8 + (int)v;
    bucket += (rl < 15) ? rl : 15;
  }
  for (int hh = 0; hh < 8; ++hh)
    dbias[hh * 4096 + d] = rel_bias[bucket * 8 + hh];
}

// -------------------- expand pos_bias output [1,H,S,S] --------------------
__global__ void posbias_kernel(const float* __restrict__ dbias, float* __restrict__ out1) {
  size_t g = (size_t)blockIdx.x * 256 + threadIdx.x;   // float4 index
  int k4 = (int)(g & 511) * 4;
  int qq = (int)((g >> 9) & 2047);
  int hh = (int)(g >> 20);
  const float* src = dbias + hh * 4096 + (k4 - qq + 2047);
  *(float4*)(out1 + g * 4) = make_float4(src[0], src[1], src[2], src[3]);
}

// -------------------- RMSNorm: fp32 in, bf16 out --------------------
__global__ void rmsnorm_bf16_kernel(const float* __restrict__ x, const float* __restrict__ w,
                                    unsigned short* __restrict__ out) {
  int tok = blockIdx.x;
  int t = threadIdx.x;  // 128
  float4 v = *(const float4*)(x + (size_t)tok * 512 + t * 4);
  float ss = v.x * v.x + v.y * v.y + v.z * v.z + v.w * v.w;
  for (int m = 1; m < 64; m <<= 1) ss += __shfl_xor(ss, m, 64);
  __shared__ float part[2];
  if ((t & 63) == 0) part[t >> 6] = ss;
  __syncthreads();
  float scale = rsqrtf((part[0] + part[1]) * (1.0f / 512.0f) + 1e-6f);
  float4 wv = *(const float4*)(w + t * 4);
  u16x4 o = {fbf(wv.x * v.x * scale), fbf(wv.y * v.y * scale),
             fbf(wv.z * v.z * scale), fbf(wv.w * v.w * scale)};
  *(u16x4*)(out + (size_t)tok * 512 + t * 4) = o;
}

// -------------------- RMSNorm: fp32 in, fp32 out (final) --------------------
__global__ void rmsnorm_f32_kernel(const float* __restrict__ x, const float* __restrict__ w,
                                   float* __restrict__ out) {
  int tok = blockIdx.x;
  int t = threadIdx.x;
  float4 v = *(const float4*)(x + (size_t)tok * 512 + t * 4);
  float ss = v.x * v.x + v.y * v.y + v.z * v.z + v.w * v.w;
  for (int m = 1; m < 64; m <<= 1) ss += __shfl_xor(ss, m, 64);
  __shared__ float part[2];
  if ((t & 63) == 0) part[t >> 6] = ss;
  __syncthreads();
  float scale = rsqrtf((part[0] + part[1]) * (1.0f / 512.0f) + 1e-6f);
  float4 wv = *(const float4*)(w + t * 4);
  *(float4*)(out + (size_t)tok * 512 + t * 4) =
      make_float4(wv.x * v.x * scale, wv.y * v.y * scale, wv.z * v.z * scale, wv.w * v.w * scale);
}

// -------------------- weight transpose+cast: src fp32 [R][C] -> dst bf16 [C][R] --------------------
__global__ void transw_kernel(const float* S0, const float* S1, const float* S2, const float* S3,
                              unsigned short* D0, unsigned short* D1, unsigned short* D2,
                              unsigned short* D3, int R, int C) {
  __shared__ float tile[32][33];
  int mat = blockIdx.z >> 2, layer = blockIdx.z & 3;
  const float* src = (mat == 0 ? S0 : mat == 1 ? S1 : mat == 2 ? S2 : S3) + (size_t)layer * R * C;
  unsigned short* dst = (mat == 0 ? D0 : mat == 1 ? D1 : mat == 2 ? D2 : D3) + (size_t)layer * R * C;
  int t = threadIdx.x;
  int r0 = blockIdx.y * 32, c0 = blockIdx.x * 32;
  int tr = t >> 3, tc = (t & 7) * 4;
  float4 v = *(const float4*)(src + (size_t)(r0 + tr) * C + c0 + tc);
  tile[tr][tc] = v.x; tile[tr][tc + 1] = v.y; tile[tr][tc + 2] = v.z; tile[tr][tc + 3] = v.w;
  __syncthreads();
  u16x4 o = {fbf(tile[tc + 0][tr]), fbf(tile[tc + 1][tr]),
             fbf(tile[tc + 2][tr]), fbf(tile[tc + 3][tr])};
  *(u16x4*)(dst + (size_t)(c0 + tr) * R + r0 + tc) = o;
}

// -------------------- bf16 MFMA GEMM: 64x64 tile, BK=64, global_load_lds dbuf ----
// mode 0: C bf16 [M][N]; mode 1: C bf16 transposed [N][M]; mode 2: C fp32 [M][N] = Res + acc
__global__ __launch_bounds__(256) void gemm64_kernel(
    const unsigned short* __restrict__ A,
    const unsigned short* B0, const unsigned short* B1, const unsigned short* B2,
    void* C0, void* C1, void* C2, const float* __restrict__ Res,
    int M, int N, int K, int m0, int m1, int m2) {
  __shared__ unsigned short As[2][64 * 64];
  __shared__ unsigned short Bs[2][64 * 64];
  const int z = blockIdx.z;
  const unsigned short* B = (z == 0) ? B0 : (z == 1) ? B1 : B2;
  void* Cptr = (z == 0) ? C0 : (z == 1) ? C1 : C2;
  const int mode = (z == 0) ? m0 : (z == 1) ? m1 : m2;
  const int t = threadIdx.x, lane = t & 63, w = t >> 6;
  const int quad = lane >> 4, c = lane & 15;
  const int wr = w >> 1, wc = w & 1;
  const int row0 = blockIdx.y * 64, col0 = blockIdx.x * 64;
  const int ar = t >> 3, aj = t & 7;
  const int asrc8 = (aj ^ (ar & 7)) * 8;
  const unsigned short* Agl = A + (size_t)(row0 + ar) * K + asrc8;
  const unsigned short* Bgl = B + (size_t)(col0 + ar) * K + asrc8;
  f32x4 acc[2][2];
#pragma unroll
  for (int i = 0; i < 2; ++i)
#pragma unroll
    for (int j = 0; j < 2; ++j) { f32x4 zz = {0.f, 0.f, 0.f, 0.f}; acc[i][j] = zz; }

  gl_lds16(Agl, &As[0][w * 512]);
  gl_lds16(Agl + 32 * (size_t)K, &As[0][2048 + w * 512]);
  gl_lds16(Bgl, &Bs[0][w * 512]);
  gl_lds16(Bgl + 32 * (size_t)K, &Bs[0][2048 + w * 512]);
  __syncthreads();

  int p = 0;
  for (int k0 = 0; k0 < K; k0 += 64) {
    if (k0 + 64 < K) {
      gl_lds16(Agl + k0 + 64, &As[p ^ 1][w * 512]);
      gl_lds16(Agl + k0 + 64 + 32 * (size_t)K, &As[p ^ 1][2048 + w * 512]);
      gl_lds16(Bgl + k0 + 64, &Bs[p ^ 1][w * 512]);
      gl_lds16(Bgl + k0 + 64 + 32 * (size_t)K, &Bs[p ^ 1][2048 + w * 512]);
    }
    s16x8 af[2][2], bf[2][2];
#pragma unroll
    for (int rb = 0; rb < 2; ++rb) {
      int r = wr * 32 + rb * 16 + c;
      int n = wc * 32 + rb * 16 + c;
#pragma unroll
      for (int ks = 0; ks < 2; ++ks) {
        af[rb][ks] = *(const s16x8*)&As[p][r * 64 + (((ks * 4 + quad) ^ (r & 7)) << 3)];
        bf[rb][ks] = *(const s16x8*)&Bs[p][n * 64 + (((ks * 4 + quad) ^ (n & 7)) << 3)];
      }
    }
#pragma unroll
    for (int rb = 0; rb < 2; ++rb)
#pragma unroll
      for (int cb = 0; cb < 2; ++cb)
#pragma unroll
        for (int ks = 0; ks < 2; ++ks)
          acc[rb][cb] = __builtin_amdgcn_mfma_f32_16x16x32_bf16(af[rb][ks], bf[cb][ks], acc[rb][cb], 0, 0, 0);
    __syncthreads();
    p ^= 1;
  }

  const int mb = row0 + wr * 32 + quad * 4;
  const int nb = col0 + wc * 32 + c;
  if (mode == 0) {
    unsigned short* Cp = (unsigned short*)Cptr;
#pragma unroll
    for (int rb = 0; rb < 2; ++rb)
#pragma unroll
      for (int cb = 0; cb < 2; ++cb) {
        size_t base = (size_t)(mb + rb * 16) * N + nb + cb * 16;
#pragma unroll
        for (int reg = 0; reg < 4; ++reg) Cp[base + (size_t)reg * N] = fbf(acc[rb][cb][reg]);
      }
  } else if (mode == 1) {
    unsigned short* Cp = (unsigned short*)Cptr;
#pragma unroll
    for (int rb = 0; rb < 2; ++rb)
#pragma unroll
      for (int cb = 0; cb < 2; ++cb) {
        u16x4 pk = {fbf(acc[rb][cb][0]), fbf(acc[rb][cb][1]), fbf(acc[rb][cb][2]), fbf(acc[rb][cb][3])};
        *(u16x4*)&Cp[(size_t)(nb + cb * 16) * M + mb + rb * 16] = pk;
      }
  } else {
    float* Cf = (float*)Cptr;
#pragma unroll
    for (int rb = 0; rb < 2; ++rb)
#pragma unroll
      for (int cb = 0; cb < 2; ++cb)
#pragma unroll
        for (int reg = 0; reg < 4; ++reg) {
          size_t o = (size_t)(mb + rb * 16 + reg) * N + nb + cb * 16;
          Cf[o] = Res[o] + acc[rb][cb][reg];
        }
  }
}

// -------------------- FFN-in GEMM (128x64, BK=64, global_load_lds dbuf) + fused gated GELU ----
__global__ __launch_bounds__(256) void gemm_ffn_kernel(
    const unsigned short* __restrict__ A, const unsigned short* __restrict__ B0g,
    const unsigned short* __restrict__ B1g, unsigned short* __restrict__ C) {
  __shared__ unsigned short As[2][128 * 64];
  __shared__ unsigned short Bs0[2][64 * 64];
  __shared__ unsigned short Bs1[2][64 * 64];
  const int t = threadIdx.x, lane = t & 63, w = t >> 6;
  const int quad = lane >> 4, c = lane & 15;
  const int wr = w >> 1, wc = w & 1;
  const int row0 = blockIdx.y * 128, col0 = blockIdx.x * 64;
  const int K = 512;
  f32x4 acc0[4][2], acc1[4][2];
#pragma unroll
  for (int i = 0; i < 4; ++i)
#pragma unroll
    for (int j = 0; j < 2; ++j) {
      f32x4 zz = {0.f, 0.f, 0.f, 0.f};
      acc0[i][j] = zz; acc1[i][j] = zz;
    }

  const int ar = t >> 3, aj = t & 7;
  const int asrc8 = (aj ^ (ar & 7)) * 8;
  const unsigned short* Agl = A + (size_t)(row0 + ar) * K + asrc8;
  const unsigned short* B0gl = B0g + (size_t)(col0 + ar) * K + asrc8;
  const unsigned short* B1gl = B1g + (size_t)(col0 + ar) * K + asrc8;

  auto stage = [&](int pp, int kk) {
    gl_lds16(Agl + kk, &As[pp][w * 512]);
    gl_lds16(Agl + kk + 32 * (size_t)K, &As[pp][2048 + w * 512]);
    gl_lds16(Agl + kk + 64 * (size_t)K, &As[pp][4096 + w * 512]);
    gl_lds16(Agl + kk + 96 * (size_t)K, &As[pp][6144 + w * 512]);
    gl_lds16(B0gl + kk, &Bs0[pp][w * 512]);
    gl_lds16(B0gl + kk + 32 * (size_t)K, &Bs0[pp][2048 + w * 512]);
    gl_lds16(B1gl + kk, &Bs1[pp][w * 512]);
    gl_lds16(B1gl + kk + 32 * (size_t)K, &Bs1[pp][2048 + w * 512]);
  };

  stage(0, 0);
  __syncthreads();

  int p = 0;
  for (int k0 = 0; k0 < K; k0 += 64) {
    if (k0 + 64 < K) stage(p ^ 1, k0 + 64);
    s16x8 af[4][2], bf0[2][2], bf1[2][2];
#pragma unroll
    for (int rb = 0; rb < 4; ++rb) {
      int r = wr * 64 + rb * 16 + c;
#pragma unroll
      for (int ks = 0; ks < 2; ++ks)
        af[rb][ks] = *(const s16x8*)&As[p][r * 64 + (((ks * 4 + quad) ^ (r & 7)) << 3)];
    }
#pragma unroll
    for (int cb = 0; cb < 2; ++cb) {
      int n = wc * 32 + cb * 16 + c;
#pragma unroll
      for (int ks = 0; ks < 2; ++ks) {
        bf0[cb][ks] = *(const s16x8*)&Bs0[p][n * 64 + (((ks * 4 + quad) ^ (n & 7)) << 3)];
        bf1[cb][ks] = *(const s16x8*)&Bs1[p][n * 64 + (((ks * 4 + quad) ^ (n & 7)) << 3)];
      }
    }
#pragma unroll
    for (int rb = 0; rb < 4; ++rb)
#pragma unroll
      for (int cb = 0; cb < 2; ++cb)
#pragma unroll
        for (int ks = 0; ks < 2; ++ks) {
          acc0[rb][cb] = __builtin_amdgcn_mfma_f32_16x16x32_bf16(af[rb][ks], bf0[cb][ks], acc0[rb][cb], 0, 0, 0);
          acc1[rb][cb] = __builtin_amdgcn_mfma_f32_16x16x32_bf16(af[rb][ks], bf1[cb][ks], acc1[rb][cb], 0, 0, 0);
        }
    __syncthreads();
    p ^= 1;
  }

  const int mb = row0 + wr * 64 + quad * 4;
  const int nb = col0 + wc * 32 + c;
#pragma unroll
  for (int rb = 0; rb < 4; ++rb)
#pragma unroll
    for (int cb = 0; cb < 2; ++cb) {
      size_t base = (size_t)(mb + rb * 16) * 1024 + nb + cb * 16;
#pragma unroll
      for (int reg = 0; reg < 4; ++reg)
        C[base + (size_t)reg * 1024] = fbf(gelu_new_f(acc0[rb][cb][reg]) * acc1[rb][cb][reg]);
    }
}

// -------------------- MFMA flash attention v2: QBLK=128 (32 q-rows/wave), split-K x4 --------
// grid (64, 8, 2): x = qtile(16) | split(4). Each block: 128 q-rows, 8 k-tiles of 64.
// Bias read directly from global dbias (L1-resident) instead of LDS broadcast.
__global__ __launch_bounds__(256) void attn_split_kernel(
    const unsigned short* __restrict__ qg, const unsigned short* __restrict__ kg,
    const unsigned short* __restrict__ vtg, const float* __restrict__ dbias,
    unsigned short* __restrict__ Op0, unsigned short* __restrict__ Op1,
    unsigned short* __restrict__ Op2, unsigned short* __restrict__ Op3,
    float* __restrict__ lsum) {
  __shared__ unsigned short Ks[64 * 64];
  __shared__ unsigned short Vs[64 * 64];
  __shared__ unsigned short Ps[4][32 * 64];
  const int b = blockIdx.z, hh = blockIdx.y;
  const int q0b = (blockIdx.x & 15) * 128;
  const int split = blockIdx.x >> 4;
  unsigned short* Op = (split == 0) ? Op0 : (split == 1) ? Op1 : (split == 2) ? Op2 : Op3;
  const int t = threadIdx.x, lane = t & 63, w = t >> 6;
  const int quad = lane >> 4, c = lane & 15;
  const int hd = hh * 64;
  // 32 q-rows per wave: rb=0/1 row-blocks of 16
  s16x8 qf[2][2];
#pragma unroll
  for (int rb = 0; rb < 2; ++rb)
#pragma unroll
    for (int ks = 0; ks < 2; ++ks)
      qf[rb][ks] = *(const s16x8*)(qg + (size_t)(b * 2048 + q0b + w * 32 + rb * 16 + c) * 512 + hd + ks * 32 + quad * 8);
  f32x4 oacc[2][4];
  float psum[2][4];
#pragma unroll
  for (int rb = 0; rb < 2; ++rb)
#pragma unroll
    for (int i = 0; i < 4; ++i) {
      f32x4 zz = {0.f, 0.f, 0.f, 0.f};
      oacc[rb][i] = zz; psum[rb][i] = 0.f;
    }
  // per-lane global bias base: dbias[h*4096 + 2047 + k - q]
  const float* dbl = dbias + hh * 4096 + 2047 + c - q0b - w * 32 - quad * 4;
  const int srow = t >> 3, sjj = t & 7;          // staging coords (+32 for v=1)
  const unsigned short* kbase = kg + (size_t)(b * 2048) * 512 + hd;
  const unsigned short* vbase = vtg + (size_t)hd * 4096 + b * 2048;

  // prefetch first tile into registers
  s16x8 kpre[2], vpre[2];
  {
    int k0 = split * 8 * 64;
#pragma unroll
    for (int v = 0; v < 2; ++v) {
      int row = srow + 32 * v;
      kpre[v] = *(const s16x8*)(kbase + (size_t)(k0 + row) * 512 + sjj * 8);
      vpre[v] = *(const s16x8*)(vbase + (size_t)row * 4096 + k0 + sjj * 8);
    }
  }

  for (int kt = split * 8; kt < split * 8 + 8; ++kt) {
    __syncthreads();   // prior iter's LDS readers done
#pragma unroll
    for (int v = 0; v < 2; ++v) {
      int row = srow + 32 * v;
      int ch = (sjj ^ (row & 7)) << 3;
      *(s16x8*)&Ks[row * 64 + ch] = kpre[v];
      *(s16x8*)&Vs[row * 64 + ch] = vpre[v];
    }
    __syncthreads();
    // prefetch next tile during compute
    {
      int k0n = (kt + 1 < split * 8 + 8) ? (kt + 1) * 64 : kt * 64;
#pragma unroll
      for (int v = 0; v < 2; ++v) {
        int row = srow + 32 * v;
        kpre[v] = *(const s16x8*)(kbase + (size_t)(k0n + row) * 512 + sjj * 8);
        vpre[v] = *(const s16x8*)(vbase + (size_t)row * 4096 + k0n + sjj * 8);
      }
    }

    // ---- QK^T: kf fragments reused across both row-blocks ----
    f32x4 s[2][4];
#pragma unroll
    for (int rb = 0; rb < 2; ++rb)
#pragma unroll
      for (int i = 0; i < 4; ++i) { f32x4 zz = {0.f, 0.f, 0.f, 0.f}; s[rb][i] = zz; }
#pragma unroll
    for (int cb = 0; cb < 4; ++cb) {
      int n = cb * 16 + c;
      s16x8 kf0 = *(const s16x8*)&Ks[n * 64 + ((quad ^ (n & 7)) << 3)];
      s16x8 kf1 = *(const s16x8*)&Ks[n * 64 + (((4 + quad) ^ (n & 7)) << 3)];
#pragma unroll
      for (int rb = 0; rb < 2; ++rb) {
        s[rb][cb] = __builtin_amdgcn_mfma_f32_16x16x32_bf16(qf[rb][0], kf0, s[rb][cb], 0, 0, 0);
        s[rb][cb] = __builtin_amdgcn_mfma_f32_16x16x32_bf16(qf[rb][1], kf1, s[rb][cb], 0, 0, 0);
      }
    }

    // ---- softmax (no-max) with global-bias loads ----
    const float* dbk = dbl + kt * 64;
#pragma unroll
    for (int rb = 0; rb < 2; ++rb)
#pragma unroll
      for (int cb = 0; cb < 4; ++cb) {
        int col = cb * 16 + c;
        int chunkbase = col >> 3;
#pragma unroll
        for (int reg = 0; reg < 4; ++reg) {
          float pp = __expf(s[rb][cb][reg] + dbk[(cb - rb) * 16 - reg]);
          psum[rb][reg] += pp;
          int rowp = rb * 16 + quad * 4 + reg;
          Ps[w][rowp * 64 + ((chunkbase ^ (rowp & 7)) << 3) + (col & 7)] = fbf(pp);
        }
      }

    // ---- PV: vf fragments reused across both row-blocks ----
    s16x8 pf[2][2];
#pragma unroll
    for (int rb = 0; rb < 2; ++rb)
#pragma unroll
      for (int ks = 0; ks < 2; ++ks)
        pf[rb][ks] = *(const s16x8*)&Ps[w][(rb * 16 + c) * 64 + (((ks * 4 + quad) ^ (c & 7)) << 3)];
#pragma unroll
    for (int cbo = 0; cbo < 4; ++cbo) {
      int n = cbo * 16 + c;
      s16x8 vf0 = *(const s16x8*)&Vs[n * 64 + ((quad ^ (n & 7)) << 3)];
      s16x8 vf1 = *(const s16x8*)&Vs[n * 64 + (((4 + quad) ^ (n & 7)) << 3)];
#pragma unroll
      for (int rb = 0; rb < 2; ++rb) {
        oacc[rb][cbo] = __builtin_amdgcn_mfma_f32_16x16x32_bf16(pf[rb][0], vf0, oacc[rb][cbo], 0, 0, 0);
        oacc[rb][cbo] = __builtin_amdgcn_mfma_f32_16x16x32_bf16(pf[rb][1], vf1, oacc[rb][cbo], 0, 0, 0);
      }
    }
  }
#pragma unroll
  for (int rb = 0; rb < 2; ++rb)
#pragma unroll
    for (int reg = 0; reg < 4; ++reg) {
      float ps = psum[rb][reg];
      ps += __shfl_xor(ps, 1, 64);
      ps += __shfl_xor(ps, 2, 64);
      ps += __shfl_xor(ps, 4, 64);
      ps += __shfl_xor(ps, 8, 64);
      psum[rb][reg] = ps;
    }
#pragma unroll
  for (int rb = 0; rb < 2; ++rb) {
    const size_t obase = ((size_t)(b * 8 + hh) * 2048 + q0b + w * 32 + rb * 16 + quad * 4);
#pragma unroll
    for (int cbo = 0; cbo < 4; ++cbo)
#pragma unroll
      for (int reg = 0; reg < 4; ++reg)
        Op[(obase + reg) * 64 + cbo * 16 + c] = fbf(oacc[rb][cbo][reg]);
    if (c == 0) {
      const size_t lbase = (size_t)split * 32768 + (size_t)(b * 8 + hh) * 2048 + q0b + w * 32 + rb * 16 + quad * 4;
#pragma unroll
      for (int reg = 0; reg < 4; ++reg) lsum[lbase + reg] = psum[rb][reg];
    }
  }
}

// -------------------- combine 4 split-K partials -> bf16 attn out [tok][h*64+dh] ------------
__global__ void attn_combine_kernel(const unsigned short* __restrict__ O0,
                                    const unsigned short* __restrict__ O1,
                                    const unsigned short* __restrict__ O2,
                                    const unsigned short* __restrict__ O3,
                                    const float* __restrict__ lsum,
                                    unsigned short* __restrict__ out) {
  int gr = blockIdx.x * 16 + (threadIdx.x >> 4);   // (b*8+h)*2048 + row, < 32768
  int d4 = (threadIdx.x & 15) * 4;
  float inv = 1.0f / (lsum[gr] + lsum[32768 + gr] + lsum[65536 + gr] + lsum[98304 + gr]);
  u16x4 p0 = *(const u16x4*)(O0 + (size_t)gr * 64 + d4);
  u16x4 p1 = *(const u16x4*)(O1 + (size_t)gr * 64 + d4);
  u16x4 p2 = *(const u16x4*)(O2 + (size_t)gr * 64 + d4);
  u16x4 p3 = *(const u16x4*)(O3 + (size_t)gr * 64 + d4);
  int bidx = gr >> 14, hidx = (gr >> 11) & 7, row = gr & 2047;
  u16x4 o;
#pragma unroll
  for (int u = 0; u < 4; ++u)
    o[u] = fbf((bf2f(p0[u]) + bf2f(p1[u]) + bf2f(p2[u]) + bf2f(p3[u])) * inv);
  *(u16x4*)(out + ((size_t)(bidx * 2048 + row) * 512) + hidx * 64 + d4) = o;
}

extern "C" void kernel_launch(void* const* d_in, const int* in_sizes, int n_in,
                              void* d_out, int out_size, void* d_ws, size_t ws_size,
                              hipStream_t stream) {
  const int*   ids      = (const int*)d_in[0];
  const float* embed    = (const float*)d_in[1];
  const float* Wq       = (const float*)d_in[2];
  const float* Wk       = (const float*)d_in[3];
  const float* Wv       = (const float*)d_in[4];
  const float* Wo       = (const float*)d_in[5];
  const float* rel_bias = (const float*)d_in[6];
  const float* wi0      = (const float*)d_in[7];
  const float* wi1      = (const float*)d_in[8];
  const float* wo_ffn   = (const float*)d_in[9];
  const float* ln0      = (const float*)d_in[10];
  const float* ln1      = (const float*)d_in[11];
  const float* final_ln = (const float*)d_in[12];
  float* out = (float*)d_out;
  char* wsb = (char*)d_ws;

  float*          x    = (float*)wsb;                              // 8 MB fp32
  unsigned short* h    = (unsigned short*)(wsb + 8388608);         // 4 MB bf16
  unsigned short* qb   = (unsigned short*)(wsb + 12582912);        // 4 MB
  unsigned short* kb   = (unsigned short*)(wsb + 16777216);        // 4 MB
  unsigned short* vt   = (unsigned short*)(wsb + 20971520);        // 4 MB
  unsigned short* wqT  = (unsigned short*)(wsb + 33554432);        // 2 MB
  unsigned short* wkT  = (unsigned short*)(wsb + 35651584);
  unsigned short* wvT  = (unsigned short*)(wsb + 37748736);
  unsigned short* woT  = (unsigned short*)(wsb + 39845888);
  unsigned short* wi0T = (unsigned short*)(wsb + 41943040);        // 4 MB
  unsigned short* wi1T = (unsigned short*)(wsb + 46137344);        // 4 MB
  unsigned short* wofT = (unsigned short*)(wsb + 50331648);        // 4 MB
  float*          dbias= (float*)(wsb + 54525952);                 // 128 KB
  unsigned short* t0b  = kb;    // 8 MB spanning kb+vt (dead during FFN)
  unsigned short* Op0  = h;                                        // h dead during attn
  unsigned short* Op1  = (unsigned short*)(wsb + 25165824);        // 4 MB
  unsigned short* Op2  = (unsigned short*)(wsb + 29360128);        // 4 MB
  unsigned short* Op3  = (unsigned short*)(wsb + 56623104);        // 4 MB
  float*          lsum = (float*)(wsb + 60817408);                 // 512 KB

  embed_kernel<<<NTOK, 128, 0, stream>>>(ids, embed, x);
  build_dbias_kernel<<<16, 256, 0, stream>>>(rel_bias, dbias);
  posbias_kernel<<<32768, 256, 0, stream>>>(dbias, out + 2097152);
  transw_kernel<<<dim3(16, 16, 16), 256, 0, stream>>>(Wq, Wk, Wv, Wo, wqT, wkT, wvT, woT, 512, 512);
  transw_kernel<<<dim3(32, 16, 8), 256, 0, stream>>>(wi0, wi1, wi0, wi0, wi0T, wi1T, wi0T, wi0T, 512, 1024);
  transw_kernel<<<dim3(16, 32, 4), 256, 0, stream>>>(wo_ffn, wo_ffn, wo_ffn, wo_ffn, wofT, wofT, wofT, wofT, 1024, 512);

  for (int l = 0; l < 4; ++l) {
    const unsigned short* wqT_l = wqT + (size_t)l * 262144;
    const unsigned short* wkT_l = wkT + (size_t)l * 262144;
    const unsigned short* wvT_l = wvT + (size_t)l * 262144;
    const unsigned short* woT_l = woT + (size_t)l * 262144;
    const unsigned short* wi0T_l = wi0T + (size_t)l * 524288;
    const unsigned short* wi1T_l = wi1T + (size_t)l * 524288;
    const unsigned short* wofT_l = wofT + (size_t)l * 524288;

    rmsnorm_bf16_kernel<<<NTOK, 128, 0, stream>>>(x, ln0 + l * 512, h);
    gemm64_kernel<<<dim3(8, 64, 3), 256, 0, stream>>>(h, wqT_l, wkT_l, wvT_l,
        qb, kb, vt, nullptr, NTOK, 512, 512, 0, 0, 1);
    attn_split_kernel<<<dim3(64, 8, 2), 256, 0, stream>>>(qb, kb, vt, dbias,
        Op0, Op1, Op2, Op3, lsum);
    attn_combine_kernel<<<2048, 256, 0, stream>>>(Op0, Op1, Op2, Op3, lsum, qb);
    gemm64_kernel<<<dim3(8, 64, 1), 256, 0, stream>>>(qb, woT_l, woT_l, woT_l,
        x, x, x, x, NTOK, 512, 512, 2, 2, 2);
    rmsnorm_bf16_kernel<<<NTOK, 128, 0, stream>>>(x, ln1 + l * 512, h);
    gemm_ffn_kernel<<<dim3(16, 32), 256, 0, stream>>>(h, wi0T_l, wi1T_l, t0b);
    gemm64_kernel<<<dim3(8, 64, 1), 256, 0, stream>>>(t0b, wofT_l, wofT_l, wofT_l,
        x, x, x, x, NTOK, 512, 1024, 2, 2, 2);
  }
  rmsnorm_f32_kernel<<<NTOK, 128, 0, stream>>>(x, final_ln, out);
}

// Round 3
// 685.959 us; speedup vs baseline: 1.1349x; 1.1349x over previous
//
#include <hip/hip_runtime.h>

#define NTOK 4096

typedef float f32x4 __attribute__((ext_vector_type(4)));
typedef short s16x8 __attribute__((ext_vector_type(8)));
typedef unsigned short u16x4 __attribute__((ext_vector_type(4)));
typedef unsigned short u16x8 __attribute__((ext_vector_type(8)));

__device__ __forceinline__ unsigned short fbf(float f) {
  unsigned int u = __float_as_uint(f);
  return (unsigned short)((u + 0x7FFFu + ((u >> 16) & 1u)) >> 16);
}
__device__ __forceinline__ float bf2f(unsigned short s) {
  return __uint_as_float(((unsigned int)s) << 16);
}
__device__ __forceinline__ float gelu_new_f(float x) {
  float inner = 0.7978845608028654f * (x + 0.044715f * x * x * x);
  return 0.5f * x * (1.0f + tanhf(inner));
}

// async global->LDS, 16B per lane. LDS dest = wave-uniform base + lane*16.
__device__ __forceinline__ void gl_lds16(const void* g, void* l) {
  __builtin_amdgcn_global_load_lds(
      (const __attribute__((address_space(1))) unsigned int*)g,
      (__attribute__((address_space(3))) unsigned int*)l, 16, 0, 0);
}

// -------------------- embedding gather (fp32 x) --------------------
__global__ void embed_kernel(const int* __restrict__ ids, const float* __restrict__ emb,
                             float* __restrict__ x) {
  int tok = blockIdx.x;
  int id = ids[tok];
  int t = threadIdx.x;
  *(float4*)(x + (size_t)tok * 512 + t * 4) = *(const float4*)(emb + (size_t)id * 512 + t * 4);
}

// -------------------- relative-position delta-bias table --------------------
__global__ void build_dbias_kernel(const float* __restrict__ rel_bias, float* __restrict__ dbias) {
  int d = blockIdx.x * 256 + threadIdx.x;
  if (d >= 4096) return;
  int rel = d - 2047;
  int bucket = (rel > 0) ? 16 : 0;
  int rp = rel < 0 ? -rel : rel;
  if (rp < 8) {
    bucket += rp;
  } else {
    float v = logf((float)rp / 8.0f) / logf(16.0f) * 8.0f;
    int rl = 8 + (int)v;
    bucket += (rl < 15) ? rl : 15;
  }
  for (int hh = 0; hh < 8; ++hh)
    dbias[hh * 4096 + d] = rel_bias[bucket * 8 + hh];
}

// -------------------- expand pos_bias output [1,H,S,S] --------------------
__global__ void posbias_kernel(const float* __restrict__ dbias, float* __restrict__ out1) {
  size_t g = (size_t)blockIdx.x * 256 + threadIdx.x;   // float4 index
  int k4 = (int)(g & 511) * 4;
  int qq = (int)((g >> 9) & 2047);
  int hh = (int)(g >> 20);
  const float* src = dbias + hh * 4096 + (k4 - qq + 2047);
  *(float4*)(out1 + g * 4) = make_float4(src[0], src[1], src[2], src[3]);
}

// -------------------- RMSNorm: fp32 in, bf16 out --------------------
__global__ void rmsnorm_bf16_kernel(const float* __restrict__ x, const float* __restrict__ w,
                                    unsigned short* __restrict__ out) {
  int tok = blockIdx.x;
  int t = threadIdx.x;  // 128
  float4 v = *(const float4*)(x + (size_t)tok * 512 + t * 4);
  float ss = v.x * v.x + v.y * v.y + v.z * v.z + v.w * v.w;
  for (int m = 1; m < 64; m <<= 1) ss += __shfl_xor(ss, m, 64);
  __shared__ float part[2];
  if ((t & 63) == 0) part[t >> 6] = ss;
  __syncthreads();
  float scale = rsqrtf((part[0] + part[1]) * (1.0f / 512.0f) + 1e-6f);
  float4 wv = *(const float4*)(w + t * 4);
  u16x4 o = {fbf(wv.x * v.x * scale), fbf(wv.y * v.y * scale),
             fbf(wv.z * v.z * scale), fbf(wv.w * v.w * scale)};
  *(u16x4*)(out + (size_t)tok * 512 + t * 4) = o;
}

// -------------------- RMSNorm: fp32 in, fp32 out (final) --------------------
__global__ void rmsnorm_f32_kernel(const float* __restrict__ x, const float* __restrict__ w,
                                   float* __restrict__ out) {
  int tok = blockIdx.x;
  int t = threadIdx.x;
  float4 v = *(const float4*)(x + (size_t)tok * 512 + t * 4);
  float ss = v.x * v.x + v.y * v.y + v.z * v.z + v.w * v.w;
  for (int m = 1; m < 64; m <<= 1) ss += __shfl_xor(ss, m, 64);
  __shared__ float part[2];
  if ((t & 63) == 0) part[t >> 6] = ss;
  __syncthreads();
  float scale = rsqrtf((part[0] + part[1]) * (1.0f / 512.0f) + 1e-6f);
  float4 wv = *(const float4*)(w + t * 4);
  *(float4*)(out + (size_t)tok * 512 + t * 4) =
      make_float4(wv.x * v.x * scale, wv.y * v.y * scale, wv.z * v.z * scale, wv.w * v.w * scale);
}

// -------------------- weight transpose+cast: src fp32 [R][C] -> dst bf16 [C][R] --------------------
__global__ void transw_kernel(const float* S0, const float* S1, const float* S2, const float* S3,
                              unsigned short* D0, unsigned short* D1, unsigned short* D2,
                              unsigned short* D3, int R, int C) {
  __shared__ float tile[32][33];
  int mat = blockIdx.z >> 2, layer = blockIdx.z & 3;
  const float* src = (mat == 0 ? S0 : mat == 1 ? S1 : mat == 2 ? S2 : S3) + (size_t)layer * R * C;
  unsigned short* dst = (mat == 0 ? D0 : mat == 1 ? D1 : mat == 2 ? D2 : D3) + (size_t)layer * R * C;
  int t = threadIdx.x;
  int r0 = blockIdx.y * 32, c0 = blockIdx.x * 32;
  int tr = t >> 3, tc = (t & 7) * 4;
  float4 v = *(const float4*)(src + (size_t)(r0 + tr) * C + c0 + tc);
  tile[tr][tc] = v.x; tile[tr][tc + 1] = v.y; tile[tr][tc + 2] = v.z; tile[tr][tc + 3] = v.w;
  __syncthreads();
  u16x4 o = {fbf(tile[tc + 0][tr]), fbf(tile[tc + 1][tr]),
             fbf(tile[tc + 2][tr]), fbf(tile[tc + 3][tr])};
  *(u16x4*)(dst + (size_t)(c0 + tr) * R + r0 + tc) = o;
}

// -------------------- bf16 MFMA GEMM: 64x64 tile, BK=64, global_load_lds dbuf ----
// mode 0: C bf16 [M][N]; mode 1: C bf16 transposed [N][M]; mode 2: C fp32 [M][N] = Res + acc
__global__ __launch_bounds__(256) void gemm64_kernel(
    const unsigned short* __restrict__ A,
    const unsigned short* B0, const unsigned short* B1, const unsigned short* B2,
    void* C0, void* C1, void* C2, const float* __restrict__ Res,
    int M, int N, int K, int m0, int m1, int m2) {
  __shared__ unsigned short As[2][64 * 64];
  __shared__ unsigned short Bs[2][64 * 64];
  const int z = blockIdx.z;
  const unsigned short* B = (z == 0) ? B0 : (z == 1) ? B1 : B2;
  void* Cptr = (z == 0) ? C0 : (z == 1) ? C1 : C2;
  const int mode = (z == 0) ? m0 : (z == 1) ? m1 : m2;
  const int t = threadIdx.x, lane = t & 63, w = t >> 6;
  const int quad = lane >> 4, c = lane & 15;
  const int wr = w >> 1, wc = w & 1;
  const int row0 = blockIdx.y * 64, col0 = blockIdx.x * 64;
  const int ar = t >> 3, aj = t & 7;
  const int asrc8 = (aj ^ (ar & 7)) * 8;
  const unsigned short* Agl = A + (size_t)(row0 + ar) * K + asrc8;
  const unsigned short* Bgl = B + (size_t)(col0 + ar) * K + asrc8;
  f32x4 acc[2][2];
#pragma unroll
  for (int i = 0; i < 2; ++i)
#pragma unroll
    for (int j = 0; j < 2; ++j) { f32x4 zz = {0.f, 0.f, 0.f, 0.f}; acc[i][j] = zz; }

  gl_lds16(Agl, &As[0][w * 512]);
  gl_lds16(Agl + 32 * (size_t)K, &As[0][2048 + w * 512]);
  gl_lds16(Bgl, &Bs[0][w * 512]);
  gl_lds16(Bgl + 32 * (size_t)K, &Bs[0][2048 + w * 512]);
  __syncthreads();

  int p = 0;
  for (int k0 = 0; k0 < K; k0 += 64) {
    if (k0 + 64 < K) {
      gl_lds16(Agl + k0 + 64, &As[p ^ 1][w * 512]);
      gl_lds16(Agl + k0 + 64 + 32 * (size_t)K, &As[p ^ 1][2048 + w * 512]);
      gl_lds16(Bgl + k0 + 64, &Bs[p ^ 1][w * 512]);
      gl_lds16(Bgl + k0 + 64 + 32 * (size_t)K, &Bs[p ^ 1][2048 + w * 512]);
    }
    s16x8 af[2][2], bf[2][2];
#pragma unroll
    for (int rb = 0; rb < 2; ++rb) {
      int r = wr * 32 + rb * 16 + c;
      int n = wc * 32 + rb * 16 + c;
#pragma unroll
      for (int ks = 0; ks < 2; ++ks) {
        af[rb][ks] = *(const s16x8*)&As[p][r * 64 + (((ks * 4 + quad) ^ (r & 7)) << 3)];
        bf[rb][ks] = *(const s16x8*)&Bs[p][n * 64 + (((ks * 4 + quad) ^ (n & 7)) << 3)];
      }
    }
#pragma unroll
    for (int rb = 0; rb < 2; ++rb)
#pragma unroll
      for (int cb = 0; cb < 2; ++cb)
#pragma unroll
        for (int ks = 0; ks < 2; ++ks)
          acc[rb][cb] = __builtin_amdgcn_mfma_f32_16x16x32_bf16(af[rb][ks], bf[cb][ks], acc[rb][cb], 0, 0, 0);
    __syncthreads();
    p ^= 1;
  }

  const int mb = row0 + wr * 32 + quad * 4;
  const int nb = col0 + wc * 32 + c;
  if (mode == 0) {
    unsigned short* Cp = (unsigned short*)Cptr;
#pragma unroll
    for (int rb = 0; rb < 2; ++rb)
#pragma unroll
      for (int cb = 0; cb < 2; ++cb) {
        size_t base = (size_t)(mb + rb * 16) * N + nb + cb * 16;
#pragma unroll
        for (int reg = 0; reg < 4; ++reg) Cp[base + (size_t)reg * N] = fbf(acc[rb][cb][reg]);
      }
  } else if (mode == 1) {
    unsigned short* Cp = (unsigned short*)Cptr;
#pragma unroll
    for (int rb = 0; rb < 2; ++rb)
#pragma unroll
      for (int cb = 0; cb < 2; ++cb) {
        u16x4 pk = {fbf(acc[rb][cb][0]), fbf(acc[rb][cb][1]), fbf(acc[rb][cb][2]), fbf(acc[rb][cb][3])};
        *(u16x4*)&Cp[(size_t)(nb + cb * 16) * M + mb + rb * 16] = pk;
      }
  } else {
    float* Cf = (float*)Cptr;
#pragma unroll
    for (int rb = 0; rb < 2; ++rb)
#pragma unroll
      for (int cb = 0; cb < 2; ++cb)
#pragma unroll
        for (int reg = 0; reg < 4; ++reg) {
          size_t o = (size_t)(mb + rb * 16 + reg) * N + nb + cb * 16;
          Cf[o] = Res[o] + acc[rb][cb][reg];
        }
  }
}

// -------------------- FFN-in GEMM (128x64, BK=64, global_load_lds dbuf) + fused gated GELU ----
__global__ __launch_bounds__(256) void gemm_ffn_kernel(
    const unsigned short* __restrict__ A, const unsigned short* __restrict__ B0g,
    const unsigned short* __restrict__ B1g, unsigned short* __restrict__ C) {
  __shared__ unsigned short As[2][128 * 64];
  __shared__ unsigned short Bs0[2][64 * 64];
  __shared__ unsigned short Bs1[2][64 * 64];
  const int t = threadIdx.x, lane = t & 63, w = t >> 6;
  const int quad = lane >> 4, c = lane & 15;
  const int wr = w >> 1, wc = w & 1;
  const int row0 = blockIdx.y * 128, col0 = blockIdx.x * 64;
  const int K = 512;
  f32x4 acc0[4][2], acc1[4][2];
#pragma unroll
  for (int i = 0; i < 4; ++i)
#pragma unroll
    for (int j = 0; j < 2; ++j) {
      f32x4 zz = {0.f, 0.f, 0.f, 0.f};
      acc0[i][j] = zz; acc1[i][j] = zz;
    }

  const int ar = t >> 3, aj = t & 7;
  const int asrc8 = (aj ^ (ar & 7)) * 8;
  const unsigned short* Agl = A + (size_t)(row0 + ar) * K + asrc8;
  const unsigned short* B0gl = B0g + (size_t)(col0 + ar) * K + asrc8;
  const unsigned short* B1gl = B1g + (size_t)(col0 + ar) * K + asrc8;

  auto stage = [&](int pp, int kk) {
    gl_lds16(Agl + kk, &As[pp][w * 512]);
    gl_lds16(Agl + kk + 32 * (size_t)K, &As[pp][2048 + w * 512]);
    gl_lds16(Agl + kk + 64 * (size_t)K, &As[pp][4096 + w * 512]);
    gl_lds16(Agl + kk + 96 * (size_t)K, &As[pp][6144 + w * 512]);
    gl_lds16(B0gl + kk, &Bs0[pp][w * 512]);
    gl_lds16(B0gl + kk + 32 * (size_t)K, &Bs0[pp][2048 + w * 512]);
    gl_lds16(B1gl + kk, &Bs1[pp][w * 512]);
    gl_lds16(B1gl + kk + 32 * (size_t)K, &Bs1[pp][2048 + w * 512]);
  };

  stage(0, 0);
  __syncthreads();

  int p = 0;
  for (int k0 = 0; k0 < K; k0 += 64) {
    if (k0 + 64 < K) stage(p ^ 1, k0 + 64);
    s16x8 af[4][2], bf0[2][2], bf1[2][2];
#pragma unroll
    for (int rb = 0; rb < 4; ++rb) {
      int r = wr * 64 + rb * 16 + c;
#pragma unroll
      for (int ks = 0; ks < 2; ++ks)
        af[rb][ks] = *(const s16x8*)&As[p][r * 64 + (((ks * 4 + quad) ^ (r & 7)) << 3)];
    }
#pragma unroll
    for (int cb = 0; cb < 2; ++cb) {
      int n = wc * 32 + cb * 16 + c;
#pragma unroll
      for (int ks = 0; ks < 2; ++ks) {
        bf0[cb][ks] = *(const s16x8*)&Bs0[p][n * 64 + (((ks * 4 + quad) ^ (n & 7)) << 3)];
        bf1[cb][ks] = *(const s16x8*)&Bs1[p][n * 64 + (((ks * 4 + quad) ^ (n & 7)) << 3)];
      }
    }
#pragma unroll
    for (int rb = 0; rb < 4; ++rb)
#pragma unroll
      for (int cb = 0; cb < 2; ++cb)
#pragma unroll
        for (int ks = 0; ks < 2; ++ks) {
          acc0[rb][cb] = __builtin_amdgcn_mfma_f32_16x16x32_bf16(af[rb][ks], bf0[cb][ks], acc0[rb][cb], 0, 0, 0);
          acc1[rb][cb] = __builtin_amdgcn_mfma_f32_16x16x32_bf16(af[rb][ks], bf1[cb][ks], acc1[rb][cb], 0, 0, 0);
        }
    __syncthreads();
    p ^= 1;
  }

  const int mb = row0 + wr * 64 + quad * 4;
  const int nb = col0 + wc * 32 + c;
#pragma unroll
  for (int rb = 0; rb < 4; ++rb)
#pragma unroll
    for (int cb = 0; cb < 2; ++cb) {
      size_t base = (size_t)(mb + rb * 16) * 1024 + nb + cb * 16;
#pragma unroll
      for (int reg = 0; reg < 4; ++reg)
        C[base + (size_t)reg * 1024] = fbf(gelu_new_f(acc0[rb][cb][reg]) * acc1[rb][cb][reg]);
    }
}

// -------------------- MFMA flash attention, split-K x4, no-max softmax, reg-prefetch --------
// grid (128, 8, 2) linearized then XCD-swizzled: all 32 q-tile blocks of one
// (b,h,split) group land on one XCD so the group's 128 KB K/V slice stays in
// that XCD's L2 (round-robin dispatch: XCD = linear_id & 7, learn_hip m09).
__global__ __launch_bounds__(256) void attn_split_kernel(
    const unsigned short* __restrict__ qg, const unsigned short* __restrict__ kg,
    const unsigned short* __restrict__ vtg, const float* __restrict__ dbias,
    unsigned short* __restrict__ Op0, unsigned short* __restrict__ Op1,
    unsigned short* __restrict__ Op2, unsigned short* __restrict__ Op3,
    float* __restrict__ lsum) {
  __shared__ unsigned short Ks[64 * 64];
  __shared__ unsigned short Vs[64 * 64];
  __shared__ unsigned short Ps[4][16 * 64];
  __shared__ float Bb[128];
  // ---- XCD-aware bijective remap: L in [0,2048) -> (b,h,split,qtile) ----
  const int L = blockIdx.x + 128 * (blockIdx.y + 8 * blockIdx.z);
  const int xcd = L & 7, sidx = L >> 3;          // sidx in [0,256)
  const int g = xcd + 8 * (sidx >> 5);           // group (b,h,split) in [0,64)
  const int qt = sidx & 31;                      // q-tile in [0,32)
  const int split = g >> 4;
  const int bh = g & 15;
  const int b = bh >> 3, hh = bh & 7;
  const int q0b = qt * 64;
  unsigned short* Op = (split == 0) ? Op0 : (split == 1) ? Op1 : (split == 2) ? Op2 : Op3;
  const int t = threadIdx.x, lane = t & 63, w = t >> 6;
  const int quad = lane >> 4, c = lane & 15;
  const int hd = hh * 64;
  s16x8 qf[2];
#pragma unroll
  for (int ks = 0; ks < 2; ++ks)
    qf[ks] = *(const s16x8*)(qg + (size_t)(b * 2048 + q0b + w * 16 + c) * 512 + hd + ks * 32 + quad * 8);
  f32x4 oacc[4];
  float psum[4];
#pragma unroll
  for (int i = 0; i < 4; ++i) {
    f32x4 zz = {0.f, 0.f, 0.f, 0.f};
    oacc[i] = zz; psum[i] = 0.f;
  }
  const int biasbase = hh * 4096 + 2047 - q0b - 63;
  const int rowloc = w * 16 + quad * 4;
  const int srow = t >> 3, sjj = t & 7;          // staging coords (+32 for v=1)
  const unsigned short* kbase = kg + (size_t)(b * 2048) * 512 + hd;
  const unsigned short* vbase = vtg + (size_t)hd * 4096 + b * 2048;

  // prefetch first tile into registers
  s16x8 kpre[2], vpre[2];
  float bpre;
  {
    int k0 = split * 8 * 64;
#pragma unroll
    for (int v = 0; v < 2; ++v) {
      int row = srow + 32 * v;
      kpre[v] = *(const s16x8*)(kbase + (size_t)(k0 + row) * 512 + sjj * 8);
      vpre[v] = *(const s16x8*)(vbase + (size_t)row * 4096 + k0 + sjj * 8);
    }
    bpre = dbias[biasbase + k0 + (t & 127)];
  }

  for (int kt = split * 8; kt < split * 8 + 8; ++kt) {
    __syncthreads();   // prior iter's LDS readers done
#pragma unroll
    for (int v = 0; v < 2; ++v) {
      int row = srow + 32 * v;
      int ch = (sjj ^ (row & 7)) << 3;
      *(s16x8*)&Ks[row * 64 + ch] = kpre[v];
      *(s16x8*)&Vs[row * 64 + ch] = vpre[v];
    }
    if (t < 128) Bb[t] = bpre;
    __syncthreads();
    // prefetch next tile during compute
    {
      int k0n = (kt + 1 < split * 8 + 8) ? (kt + 1) * 64 : kt * 64;
#pragma unroll
      for (int v = 0; v < 2; ++v) {
        int row = srow + 32 * v;
        kpre[v] = *(const s16x8*)(kbase + (size_t)(k0n + row) * 512 + sjj * 8);
        vpre[v] = *(const s16x8*)(vbase + (size_t)row * 4096 + k0n + sjj * 8);
      }
      bpre = dbias[biasbase + k0n + (t & 127)];
    }

    f32x4 s[4];
#pragma unroll
    for (int i = 0; i < 4; ++i) { f32x4 zz = {0.f, 0.f, 0.f, 0.f}; s[i] = zz; }
#pragma unroll
    for (int ks = 0; ks < 2; ++ks)
#pragma unroll
      for (int cb = 0; cb < 4; ++cb) {
        int n = cb * 16 + c;
        s16x8 kf = *(const s16x8*)&Ks[n * 64 + (((ks * 4 + quad) ^ (n & 7)) << 3)];
        s[cb] = __builtin_amdgcn_mfma_f32_16x16x32_bf16(qf[ks], kf, s[cb], 0, 0, 0);
      }
#pragma unroll
    for (int cb = 0; cb < 4; ++cb) {
      int col = cb * 16 + c;
      int chunkbase = (col >> 3);
#pragma unroll
      for (int reg = 0; reg < 4; ++reg) {
        float pp = __expf(s[cb][reg] + Bb[col - rowloc - reg + 63]);
        psum[reg] += pp;
        int rowp = quad * 4 + reg;
        Ps[w][rowp * 64 + ((chunkbase ^ (rowp & 7)) << 3) + (col & 7)] = fbf(pp);
      }
    }
#pragma unroll
    for (int ks = 0; ks < 2; ++ks) {
      s16x8 pf = *(const s16x8*)&Ps[w][c * 64 + (((ks * 4 + quad) ^ (c & 7)) << 3)];
#pragma unroll
      for (int cbo = 0; cbo < 4; ++cbo) {
        int n = cbo * 16 + c;
        s16x8 vf = *(const s16x8*)&Vs[n * 64 + (((ks * 4 + quad) ^ (n & 7)) << 3)];
        oacc[cbo] = __builtin_amdgcn_mfma_f32_16x16x32_bf16(pf, vf, oacc[cbo], 0, 0, 0);
      }
    }
  }
#pragma unroll
  for (int reg = 0; reg < 4; ++reg) {
    float ps = psum[reg];
    ps += __shfl_xor(ps, 1, 64);
    ps += __shfl_xor(ps, 2, 64);
    ps += __shfl_xor(ps, 4, 64);
    ps += __shfl_xor(ps, 8, 64);
    psum[reg] = ps;
  }
  const size_t obase = ((size_t)(b * 8 + hh) * 2048 + q0b + w * 16 + quad * 4);
#pragma unroll
  for (int cbo = 0; cbo < 4; ++cbo)
#pragma unroll
    for (int reg = 0; reg < 4; ++reg)
      Op[(obase + reg) * 64 + cbo * 16 + c] = fbf(oacc[cbo][reg]);
  if (c == 0) {
    const size_t lbase = (size_t)split * 32768 + (size_t)(b * 8 + hh) * 2048 + q0b + w * 16 + quad * 4;
#pragma unroll
    for (int reg = 0; reg < 4; ++reg) lsum[lbase + reg] = psum[reg];
  }
}

// -------------------- combine 4 split-K partials -> bf16 attn out [tok][h*64+dh] ------------
__global__ void attn_combine_kernel(const unsigned short* __restrict__ O0,
                                    const unsigned short* __restrict__ O1,
                                    const unsigned short* __restrict__ O2,
                                    const unsigned short* __restrict__ O3,
                                    const float* __restrict__ lsum,
                                    unsigned short* __restrict__ out) {
  int gr = blockIdx.x * 16 + (threadIdx.x >> 4);   // (b*8+h)*2048 + row, < 32768
  int d4 = (threadIdx.x & 15) * 4;
  float inv = 1.0f / (lsum[gr] + lsum[32768 + gr] + lsum[65536 + gr] + lsum[98304 + gr]);
  u16x4 p0 = *(const u16x4*)(O0 + (size_t)gr * 64 + d4);
  u16x4 p1 = *(const u16x4*)(O1 + (size_t)gr * 64 + d4);
  u16x4 p2 = *(const u16x4*)(O2 + (size_t)gr * 64 + d4);
  u16x4 p3 = *(const u16x4*)(O3 + (size_t)gr * 64 + d4);
  int bidx = gr >> 14, hidx = (gr >> 11) & 7, row = gr & 2047;
  u16x4 o;
#pragma unroll
  for (int u = 0; u < 4; ++u)
    o[u] = fbf((bf2f(p0[u]) + bf2f(p1[u]) + bf2f(p2[u]) + bf2f(p3[u])) * inv);
  *(u16x4*)(out + ((size_t)(bidx * 2048 + row) * 512) + hidx * 64 + d4) = o;
}

extern "C" void kernel_launch(void* const* d_in, const int* in_sizes, int n_in,
                              void* d_out, int out_size, void* d_ws, size_t ws_size,
                              hipStream_t stream) {
  const int*   ids      = (const int*)d_in[0];
  const float* embed    = (const float*)d_in[1];
  const float* Wq       = (const float*)d_in[2];
  const float* Wk       = (const float*)d_in[3];
  const float* Wv       = (const float*)d_in[4];
  const float* Wo       = (const float*)d_in[5];
  const float* rel_bias = (const float*)d_in[6];
  const float* wi0      = (const float*)d_in[7];
  const float* wi1      = (const float*)d_in[8];
  const float* wo_ffn   = (const float*)d_in[9];
  const float* ln0      = (const float*)d_in[10];
  const float* ln1      = (const float*)d_in[11];
  const float* final_ln = (const float*)d_in[12];
  float* out = (float*)d_out;
  char* wsb = (char*)d_ws;

  float*          x    = (float*)wsb;                              // 8 MB fp32
  unsigned short* h    = (unsigned short*)(wsb + 8388608);         // 4 MB bf16
  unsigned short* qb   = (unsigned short*)(wsb + 12582912);        // 4 MB
  unsigned short* kb   = (unsigned short*)(wsb + 16777216);        // 4 MB
  unsigned short* vt   = (unsigned short*)(wsb + 20971520);        // 4 MB
  unsigned short* wqT  = (unsigned short*)(wsb + 33554432);        // 2 MB
  unsigned short* wkT  = (unsigned short*)(wsb + 35651584);
  unsigned short* wvT  = (unsigned short*)(wsb + 37748736);
  unsigned short* woT  = (unsigned short*)(wsb + 39845888);
  unsigned short* wi0T = (unsigned short*)(wsb + 41943040);        // 4 MB
  unsigned short* wi1T = (unsigned short*)(wsb + 46137344);        // 4 MB
  unsigned short* wofT = (unsigned short*)(wsb + 50331648);        // 4 MB
  float*          dbias= (float*)(wsb + 54525952);                 // 128 KB
  unsigned short* t0b  = kb;    // 8 MB spanning kb+vt (dead during FFN)
  unsigned short* Op0  = h;                                        // h dead during attn
  unsigned short* Op1  = (unsigned short*)(wsb + 25165824);        // 4 MB
  unsigned short* Op2  = (unsigned short*)(wsb + 29360128);        // 4 MB
  unsigned short* Op3  = (unsigned short*)(wsb + 56623104);        // 4 MB
  float*          lsum = (float*)(wsb + 60817408);                 // 512 KB

  embed_kernel<<<NTOK, 128, 0, stream>>>(ids, embed, x);
  build_dbias_kernel<<<16, 256, 0, stream>>>(rel_bias, dbias);
  posbias_kernel<<<32768, 256, 0, stream>>>(dbias, out + 2097152);
  transw_kernel<<<dim3(16, 16, 16), 256, 0, stream>>>(Wq, Wk, Wv, Wo, wqT, wkT, wvT, woT, 512, 512);
  transw_kernel<<<dim3(32, 16, 8), 256, 0, stream>>>(wi0, wi1, wi0, wi0, wi0T, wi1T, wi0T, wi0T, 512, 1024);
  transw_kernel<<<dim3(16, 32, 4), 256, 0, stream>>>(wo_ffn, wo_ffn, wo_ffn, wo_ffn, wofT, wofT, wofT, wofT, 1024, 512);

  for (int l = 0; l < 4; ++l) {
    const unsigned short* wqT_l = wqT + (size_t)l * 262144;
    const unsigned short* wkT_l = wkT + (size_t)l * 262144;
    const unsigned short* wvT_l = wvT + (size_t)l * 262144;
    const unsigned short* woT_l = woT + (size_t)l * 262144;
    const unsigned short* wi0T_l = wi0T + (size_t)l * 524288;
    const unsigned short* wi1T_l = wi1T + (size_t)l * 524288;
    const unsigned short* wofT_l = wofT + (size_t)l * 524288;

    rmsnorm_bf16_kernel<<<NTOK, 128, 0, stream>>>(x, ln0 + l * 512, h);
    gemm64_kernel<<<dim3(8, 64, 3), 256, 0, stream>>>(h, wqT_l, wkT_l, wvT_l,
        qb, kb, vt, nullptr, NTOK, 512, 512, 0, 0, 1);
    attn_split_kernel<<<dim3(128, 8, 2), 256, 0, stream>>>(qb, kb, vt, dbias,
        Op0, Op1, Op2, Op3, lsum);
    attn_combine_kernel<<<2048, 256, 0, stream>>>(Op0, Op1, Op2, Op3, lsum, qb);
    gemm64_kernel<<<dim3(8, 64, 1), 256, 0, stream>>>(qb, woT_l, woT_l, woT_l,
        x, x, x, x, NTOK, 512, 512, 2, 2, 2);
    rmsnorm_bf16_kernel<<<NTOK, 128, 0, stream>>>(x, ln1 + l * 512, h);
    gemm_ffn_kernel<<<dim3(16, 32), 256, 0, stream>>>(h, wi0T_l, wi1T_l, t0b);
    gemm64_kernel<<<dim3(8, 64, 1), 256, 0, stream>>>(t0b, wofT_l, wofT_l, wofT_l,
        x, x, x, x, NTOK, 512, 1024, 2, 2, 2);
  }
  rmsnorm_f32_kernel<<<NTOK, 128, 0, stream>>>(x, final_ln, out);
}

// Round 4
// 685.638 us; speedup vs baseline: 1.1354x; 1.0005x over previous
//
#include <hip/hip_runtime.h>

#define NTOK 4096

typedef float f32x4 __attribute__((ext_vector_type(4)));
typedef short s16x8 __attribute__((ext_vector_type(8)));
typedef unsigned short u16x4 __attribute__((ext_vector_type(4)));
typedef unsigned short u16x8 __attribute__((ext_vector_type(8)));

__device__ __forceinline__ unsigned short fbf(float f) {
  unsigned int u = __float_as_uint(f);
  return (unsigned short)((u + 0x7FFFu + ((u >> 16) & 1u)) >> 16);
}
__device__ __forceinline__ float bf2f(unsigned short s) {
  return __uint_as_float(((unsigned int)s) << 16);
}
__device__ __forceinline__ float gelu_new_f(float x) {
  float inner = 0.7978845608028654f * (x + 0.044715f * x * x * x);
  return 0.5f * x * (1.0f + tanhf(inner));
}

// async global->LDS, 16B per lane. LDS dest = wave-uniform base + lane*16.
__device__ __forceinline__ void gl_lds16(const void* g, void* l) {
  __builtin_amdgcn_global_load_lds(
      (const __attribute__((address_space(1))) unsigned int*)g,
      (__attribute__((address_space(3))) unsigned int*)l, 16, 0, 0);
}

// -------------------- embedding gather (fp32 x) --------------------
__global__ void embed_kernel(const int* __restrict__ ids, const float* __restrict__ emb,
                             float* __restrict__ x) {
  int tok = blockIdx.x;
  int id = ids[tok];
  int t = threadIdx.x;
  *(float4*)(x + (size_t)tok * 512 + t * 4) = *(const float4*)(emb + (size_t)id * 512 + t * 4);
}

// -------------------- relative-position delta-bias table --------------------
__global__ void build_dbias_kernel(const float* __restrict__ rel_bias, float* __restrict__ dbias) {
  int d = blockIdx.x * 256 + threadIdx.x;
  if (d >= 4096) return;
  int rel = d - 2047;
  int bucket = (rel > 0) ? 16 : 0;
  int rp = rel < 0 ? -rel : rel;
  if (rp < 8) {
    bucket += rp;
  } else {
    float v = logf((float)rp / 8.0f) / logf(16.0f) * 8.0f;
    int rl = 8 + (int)v;
    bucket += (rl < 15) ? rl : 15;
  }
  for (int hh = 0; hh < 8; ++hh)
    dbias[hh * 4096 + d] = rel_bias[bucket * 8 + hh];
}

// -------------------- expand pos_bias output [1,H,S,S] --------------------
__global__ void posbias_kernel(const float* __restrict__ dbias, float* __restrict__ out1) {
  size_t g = (size_t)blockIdx.x * 256 + threadIdx.x;   // float4 index
  int k4 = (int)(g & 511) * 4;
  int qq = (int)((g >> 9) & 2047);
  int hh = (int)(g >> 20);
  const float* src = dbias + hh * 4096 + (k4 - qq + 2047);
  *(float4*)(out1 + g * 4) = make_float4(src[0], src[1], src[2], src[3]);
}

// -------------------- RMSNorm: fp32 in, bf16 out --------------------
__global__ void rmsnorm_bf16_kernel(const float* __restrict__ x, const float* __restrict__ w,
                                    unsigned short* __restrict__ out) {
  int tok = blockIdx.x;
  int t = threadIdx.x;  // 128
  float4 v = *(const float4*)(x + (size_t)tok * 512 + t * 4);
  float ss = v.x * v.x + v.y * v.y + v.z * v.z + v.w * v.w;
  for (int m = 1; m < 64; m <<= 1) ss += __shfl_xor(ss, m, 64);
  __shared__ float part[2];
  if ((t & 63) == 0) part[t >> 6] = ss;
  __syncthreads();
  float scale = rsqrtf((part[0] + part[1]) * (1.0f / 512.0f) + 1e-6f);
  float4 wv = *(const float4*)(w + t * 4);
  u16x4 o = {fbf(wv.x * v.x * scale), fbf(wv.y * v.y * scale),
             fbf(wv.z * v.z * scale), fbf(wv.w * v.w * scale)};
  *(u16x4*)(out + (size_t)tok * 512 + t * 4) = o;
}

// -------------------- RMSNorm: fp32 in, fp32 out (final) --------------------
__global__ void rmsnorm_f32_kernel(const float* __restrict__ x, const float* __restrict__ w,
                                   float* __restrict__ out) {
  int tok = blockIdx.x;
  int t = threadIdx.x;
  float4 v = *(const float4*)(x + (size_t)tok * 512 + t * 4);
  float ss = v.x * v.x + v.y * v.y + v.z * v.z + v.w * v.w;
  for (int m = 1; m < 64; m <<= 1) ss += __shfl_xor(ss, m, 64);
  __shared__ float part[2];
  if ((t & 63) == 0) part[t >> 6] = ss;
  __syncthreads();
  float scale = rsqrtf((part[0] + part[1]) * (1.0f / 512.0f) + 1e-6f);
  float4 wv = *(const float4*)(w + t * 4);
  *(float4*)(out + (size_t)tok * 512 + t * 4) =
      make_float4(wv.x * v.x * scale, wv.y * v.y * scale, wv.z * v.z * scale, wv.w * v.w * scale);
}

// -------------------- weight transpose+cast: src fp32 [R][C] -> dst bf16 [C][R] --------------------
__global__ void transw_kernel(const float* S0, const float* S1, const float* S2, const float* S3,
                              unsigned short* D0, unsigned short* D1, unsigned short* D2,
                              unsigned short* D3, int R, int C) {
  __shared__ float tile[32][33];
  int mat = blockIdx.z >> 2, layer = blockIdx.z & 3;
  const float* src = (mat == 0 ? S0 : mat == 1 ? S1 : mat == 2 ? S2 : S3) + (size_t)layer * R * C;
  unsigned short* dst = (mat == 0 ? D0 : mat == 1 ? D1 : mat == 2 ? D2 : D3) + (size_t)layer * R * C;
  int t = threadIdx.x;
  int r0 = blockIdx.y * 32, c0 = blockIdx.x * 32;
  int tr = t >> 3, tc = (t & 7) * 4;
  float4 v = *(const float4*)(src + (size_t)(r0 + tr) * C + c0 + tc);
  tile[tr][tc] = v.x; tile[tr][tc + 1] = v.y; tile[tr][tc + 2] = v.z; tile[tr][tc + 3] = v.w;
  __syncthreads();
  u16x4 o = {fbf(tile[tc + 0][tr]), fbf(tile[tc + 1][tr]),
             fbf(tile[tc + 2][tr]), fbf(tile[tc + 3][tr])};
  *(u16x4*)(dst + (size_t)(c0 + tr) * R + r0 + tc) = o;
}

// -------------------- bf16 MFMA GEMM: 128x64 tile, BK=64, global_load_lds dbuf ----
// Single-B clone of the verified gemm_ffn structure (12 ds_read : 16 MFMA per k-step).
// mode 0: C bf16 [M][N]; mode 1: C bf16 transposed [N][M]; mode 2: C fp32 [M][N] = Res + acc
__global__ __launch_bounds__(256) void gemm128_kernel(
    const unsigned short* __restrict__ A,
    const unsigned short* B0, const unsigned short* B1, const unsigned short* B2,
    void* C0, void* C1, void* C2, const float* __restrict__ Res,
    int M, int N, int K, int m0, int m1, int m2) {
  __shared__ unsigned short As[2][128 * 64];
  __shared__ unsigned short Bs[2][64 * 64];
  const int z = blockIdx.z;
  const unsigned short* B = (z == 0) ? B0 : (z == 1) ? B1 : B2;
  void* Cptr = (z == 0) ? C0 : (z == 1) ? C1 : C2;
  const int mode = (z == 0) ? m0 : (z == 1) ? m1 : m2;
  const int t = threadIdx.x, lane = t & 63, w = t >> 6;
  const int quad = lane >> 4, c = lane & 15;
  const int wr = w >> 1, wc = w & 1;
  const int row0 = blockIdx.y * 128, col0 = blockIdx.x * 64;
  f32x4 acc[4][2];
#pragma unroll
  for (int i = 0; i < 4; ++i)
#pragma unroll
    for (int j = 0; j < 2; ++j) { f32x4 zz = {0.f, 0.f, 0.f, 0.f}; acc[i][j] = zz; }

  const int ar = t >> 3, aj = t & 7;
  const int asrc8 = (aj ^ (ar & 7)) * 8;
  const unsigned short* Agl = A + (size_t)(row0 + ar) * K + asrc8;
  const unsigned short* Bgl = B + (size_t)(col0 + ar) * K + asrc8;

  auto stage = [&](int pp, int kk) {
    gl_lds16(Agl + kk, &As[pp][w * 512]);
    gl_lds16(Agl + kk + 32 * (size_t)K, &As[pp][2048 + w * 512]);
    gl_lds16(Agl + kk + 64 * (size_t)K, &As[pp][4096 + w * 512]);
    gl_lds16(Agl + kk + 96 * (size_t)K, &As[pp][6144 + w * 512]);
    gl_lds16(Bgl + kk, &Bs[pp][w * 512]);
    gl_lds16(Bgl + kk + 32 * (size_t)K, &Bs[pp][2048 + w * 512]);
  };

  stage(0, 0);
  __syncthreads();

  int p = 0;
  for (int k0 = 0; k0 < K; k0 += 64) {
    if (k0 + 64 < K) stage(p ^ 1, k0 + 64);
    s16x8 af[4][2], bf[2][2];
#pragma unroll
    for (int rb = 0; rb < 4; ++rb) {
      int r = wr * 64 + rb * 16 + c;
#pragma unroll
      for (int ks = 0; ks < 2; ++ks)
        af[rb][ks] = *(const s16x8*)&As[p][r * 64 + (((ks * 4 + quad) ^ (r & 7)) << 3)];
    }
#pragma unroll
    for (int cb = 0; cb < 2; ++cb) {
      int n = wc * 32 + cb * 16 + c;
#pragma unroll
      for (int ks = 0; ks < 2; ++ks)
        bf[cb][ks] = *(const s16x8*)&Bs[p][n * 64 + (((ks * 4 + quad) ^ (n & 7)) << 3)];
    }
#pragma unroll
    for (int rb = 0; rb < 4; ++rb)
#pragma unroll
      for (int cb = 0; cb < 2; ++cb)
#pragma unroll
        for (int ks = 0; ks < 2; ++ks)
          acc[rb][cb] = __builtin_amdgcn_mfma_f32_16x16x32_bf16(af[rb][ks], bf[cb][ks], acc[rb][cb], 0, 0, 0);
    __syncthreads();
    p ^= 1;
  }

  const int mb = row0 + wr * 64 + quad * 4;
  const int nb = col0 + wc * 32 + c;
  if (mode == 0) {
    unsigned short* Cp = (unsigned short*)Cptr;
#pragma unroll
    for (int rb = 0; rb < 4; ++rb)
#pragma unroll
      for (int cb = 0; cb < 2; ++cb) {
        size_t base = (size_t)(mb + rb * 16) * N + nb + cb * 16;
#pragma unroll
        for (int reg = 0; reg < 4; ++reg) Cp[base + (size_t)reg * N] = fbf(acc[rb][cb][reg]);
      }
  } else if (mode == 1) {
    unsigned short* Cp = (unsigned short*)Cptr;
#pragma unroll
    for (int rb = 0; rb < 4; ++rb)
#pragma unroll
      for (int cb = 0; cb < 2; ++cb) {
        u16x4 pk = {fbf(acc[rb][cb][0]), fbf(acc[rb][cb][1]), fbf(acc[rb][cb][2]), fbf(acc[rb][cb][3])};
        *(u16x4*)&Cp[(size_t)(nb + cb * 16) * M + mb + rb * 16] = pk;
      }
  } else {
    float* Cf = (float*)Cptr;
#pragma unroll
    for (int rb = 0; rb < 4; ++rb)
#pragma unroll
      for (int cb = 0; cb < 2; ++cb)
#pragma unroll
        for (int reg = 0; reg < 4; ++reg) {
          size_t o = (size_t)(mb + rb * 16 + reg) * N + nb + cb * 16;
          Cf[o] = Res[o] + acc[rb][cb][reg];
        }
  }
}

// -------------------- FFN-in GEMM (128x64, BK=64, global_load_lds dbuf) + fused gated GELU ----
__global__ __launch_bounds__(256) void gemm_ffn_kernel(
    const unsigned short* __restrict__ A, const unsigned short* __restrict__ B0g,
    const unsigned short* __restrict__ B1g, unsigned short* __restrict__ C) {
  __shared__ unsigned short As[2][128 * 64];
  __shared__ unsigned short Bs0[2][64 * 64];
  __shared__ unsigned short Bs1[2][64 * 64];
  const int t = threadIdx.x, lane = t & 63, w = t >> 6;
  const int quad = lane >> 4, c = lane & 15;
  const int wr = w >> 1, wc = w & 1;
  const int row0 = blockIdx.y * 128, col0 = blockIdx.x * 64;
  const int K = 512;
  f32x4 acc0[4][2], acc1[4][2];
#pragma unroll
  for (int i = 0; i < 4; ++i)
#pragma unroll
    for (int j = 0; j < 2; ++j) {
      f32x4 zz = {0.f, 0.f, 0.f, 0.f};
      acc0[i][j] = zz; acc1[i][j] = zz;
    }

  const int ar = t >> 3, aj = t & 7;
  const int asrc8 = (aj ^ (ar & 7)) * 8;
  const unsigned short* Agl = A + (size_t)(row0 + ar) * K + asrc8;
  const unsigned short* B0gl = B0g + (size_t)(col0 + ar) * K + asrc8;
  const unsigned short* B1gl = B1g + (size_t)(col0 + ar) * K + asrc8;

  auto stage = [&](int pp, int kk) {
    gl_lds16(Agl + kk, &As[pp][w * 512]);
    gl_lds16(Agl + kk + 32 * (size_t)K, &As[pp][2048 + w * 512]);
    gl_lds16(Agl + kk + 64 * (size_t)K, &As[pp][4096 + w * 512]);
    gl_lds16(Agl + kk + 96 * (size_t)K, &As[pp][6144 + w * 512]);
    gl_lds16(B0gl + kk, &Bs0[pp][w * 512]);
    gl_lds16(B0gl + kk + 32 * (size_t)K, &Bs0[pp][2048 + w * 512]);
    gl_lds16(B1gl + kk, &Bs1[pp][w * 512]);
    gl_lds16(B1gl + kk + 32 * (size_t)K, &Bs1[pp][2048 + w * 512]);
  };

  stage(0, 0);
  __syncthreads();

  int p = 0;
  for (int k0 = 0; k0 < K; k0 += 64) {
    if (k0 + 64 < K) stage(p ^ 1, k0 + 64);
    s16x8 af[4][2], bf0[2][2], bf1[2][2];
#pragma unroll
    for (int rb = 0; rb < 4; ++rb) {
      int r = wr * 64 + rb * 16 + c;
#pragma unroll
      for (int ks = 0; ks < 2; ++ks)
        af[rb][ks] = *(const s16x8*)&As[p][r * 64 + (((ks * 4 + quad) ^ (r & 7)) << 3)];
    }
#pragma unroll
    for (int cb = 0; cb < 2; ++cb) {
      int n = wc * 32 + cb * 16 + c;
#pragma unroll
      for (int ks = 0; ks < 2; ++ks) {
        bf0[cb][ks] = *(const s16x8*)&Bs0[p][n * 64 + (((ks * 4 + quad) ^ (n & 7)) << 3)];
        bf1[cb][ks] = *(const s16x8*)&Bs1[p][n * 64 + (((ks * 4 + quad) ^ (n & 7)) << 3)];
      }
    }
#pragma unroll
    for (int rb = 0; rb < 4; ++rb)
#pragma unroll
      for (int cb = 0; cb < 2; ++cb)
#pragma unroll
        for (int ks = 0; ks < 2; ++ks) {
          acc0[rb][cb] = __builtin_amdgcn_mfma_f32_16x16x32_bf16(af[rb][ks], bf0[cb][ks], acc0[rb][cb], 0, 0, 0);
          acc1[rb][cb] = __builtin_amdgcn_mfma_f32_16x16x32_bf16(af[rb][ks], bf1[cb][ks], acc1[rb][cb], 0, 0, 0);
        }
    __syncthreads();
    p ^= 1;
  }

  const int mb = row0 + wr * 64 + quad * 4;
  const int nb = col0 + wc * 32 + c;
#pragma unroll
  for (int rb = 0; rb < 4; ++rb)
#pragma unroll
    for (int cb = 0; cb < 2; ++cb) {
      size_t base = (size_t)(mb + rb * 16) * 1024 + nb + cb * 16;
#pragma unroll
      for (int reg = 0; reg < 4; ++reg)
        C[base + (size_t)reg * 1024] = fbf(gelu_new_f(acc0[rb][cb][reg]) * acc1[rb][cb][reg]);
    }
}

// -------------------- MFMA flash attention, split-K x4, no-max softmax -----------------------
// grid (128, 8, 2): x = qtile(32) | split(4). Each block: 64 q-rows, 8 k-tiles of 64.
// K/V/bias double-buffered in LDS: ONE barrier per k-tile, prefetch 2 tiles deep.
__global__ __launch_bounds__(256) void attn_split_kernel(
    const unsigned short* __restrict__ qg, const unsigned short* __restrict__ kg,
    const unsigned short* __restrict__ vtg, const float* __restrict__ dbias,
    unsigned short* __restrict__ Op0, unsigned short* __restrict__ Op1,
    unsigned short* __restrict__ Op2, unsigned short* __restrict__ Op3,
    float* __restrict__ lsum) {
  __shared__ unsigned short Ks[2][64 * 64];
  __shared__ unsigned short Vs[2][64 * 64];
  __shared__ unsigned short Ps[4][16 * 64];
  __shared__ float Bb[2][128];
  const int b = blockIdx.z, hh = blockIdx.y;
  const int q0b = (blockIdx.x & 31) * 64;
  const int split = blockIdx.x >> 5;
  unsigned short* Op = (split == 0) ? Op0 : (split == 1) ? Op1 : (split == 2) ? Op2 : Op3;
  const int t = threadIdx.x, lane = t & 63, w = t >> 6;
  const int quad = lane >> 4, c = lane & 15;
  const int hd = hh * 64;
  s16x8 qf[2];
#pragma unroll
  for (int ks = 0; ks < 2; ++ks)
    qf[ks] = *(const s16x8*)(qg + (size_t)(b * 2048 + q0b + w * 16 + c) * 512 + hd + ks * 32 + quad * 8);
  f32x4 oacc[4];
  float psum[4];
#pragma unroll
  for (int i = 0; i < 4; ++i) {
    f32x4 zz = {0.f, 0.f, 0.f, 0.f};
    oacc[i] = zz; psum[i] = 0.f;
  }
  const int biasbase = hh * 4096 + 2047 - q0b - 63;
  const int rowloc = w * 16 + quad * 4;
  const int srow = t >> 3, sjj = t & 7;          // staging coords (+32 for v=1)
  const unsigned short* kbase = kg + (size_t)(b * 2048) * 512 + hd;
  const unsigned short* vbase = vtg + (size_t)hd * 4096 + b * 2048;
  const int kt0 = split * 8;

  s16x8 kpre[2], vpre[2];
  float bpre;
  auto ldtile = [&](int kt) {   // tile kt -> registers
    int k0 = kt * 64;
#pragma unroll
    for (int v = 0; v < 2; ++v) {
      int row = srow + 32 * v;
      kpre[v] = *(const s16x8*)(kbase + (size_t)(k0 + row) * 512 + sjj * 8);
      vpre[v] = *(const s16x8*)(vbase + (size_t)row * 4096 + k0 + sjj * 8);
    }
    bpre = dbias[biasbase + k0 + (t & 127)];
  };
  auto sttile = [&](int buf) {  // registers -> LDS buffer
#pragma unroll
    for (int v = 0; v < 2; ++v) {
      int row = srow + 32 * v;
      int ch = (sjj ^ (row & 7)) << 3;
      *(s16x8*)&Ks[buf][row * 64 + ch] = kpre[v];
      *(s16x8*)&Vs[buf][row * 64 + ch] = vpre[v];
    }
    if (t < 128) Bb[buf][t] = bpre;
  };

  ldtile(kt0);
  sttile(0);
  ldtile(kt0 + 1);
  __syncthreads();   // buf0 visible

  for (int kt = 0; kt < 8; ++kt) {
    const int cur = kt & 1;
    if (kt < 7) {
      sttile(cur ^ 1);                 // tile kt+1 (in regs) -> other buffer
      if (kt < 6) ldtile(kt0 + kt + 2);  // issue tile kt+2 loads (drained by end barrier)
    }

    f32x4 s[4];
#pragma unroll
    for (int i = 0; i < 4; ++i) { f32x4 zz = {0.f, 0.f, 0.f, 0.f}; s[i] = zz; }
#pragma unroll
    for (int ks = 0; ks < 2; ++ks)
#pragma unroll
      for (int cb = 0; cb < 4; ++cb) {
        int n = cb * 16 + c;
        s16x8 kf = *(const s16x8*)&Ks[cur][n * 64 + (((ks * 4 + quad) ^ (n & 7)) << 3)];
        s[cb] = __builtin_amdgcn_mfma_f32_16x16x32_bf16(qf[ks], kf, s[cb], 0, 0, 0);
      }
#pragma unroll
    for (int cb = 0; cb < 4; ++cb) {
      int col = cb * 16 + c;
      int chunkbase = (col >> 3);
#pragma unroll
      for (int reg = 0; reg < 4; ++reg) {
        float pp = __expf(s[cb][reg] + Bb[cur][col - rowloc - reg + 63]);
        psum[reg] += pp;
        int rowp = quad * 4 + reg;
        Ps[w][rowp * 64 + ((chunkbase ^ (rowp & 7)) << 3) + (col & 7)] = fbf(pp);
      }
    }
#pragma unroll
    for (int ks = 0; ks < 2; ++ks) {
      s16x8 pf = *(const s16x8*)&Ps[w][c * 64 + (((ks * 4 + quad) ^ (c & 7)) << 3)];
#pragma unroll
      for (int cbo = 0; cbo < 4; ++cbo) {
        int n = cbo * 16 + c;
        s16x8 vf = *(const s16x8*)&Vs[cur][n * 64 + (((ks * 4 + quad) ^ (n & 7)) << 3)];
        oacc[cbo] = __builtin_amdgcn_mfma_f32_16x16x32_bf16(pf, vf, oacc[cbo], 0, 0, 0);
      }
    }
    __syncthreads();   // writes of buf cur^1 visible; cur readers done before next overwrite
  }
#pragma unroll
  for (int reg = 0; reg < 4; ++reg) {
    float ps = psum[reg];
    ps += __shfl_xor(ps, 1, 64);
    ps += __shfl_xor(ps, 2, 64);
    ps += __shfl_xor(ps, 4, 64);
    ps += __shfl_xor(ps, 8, 64);
    psum[reg] = ps;
  }
  const size_t obase = ((size_t)(b * 8 + hh) * 2048 + q0b + w * 16 + quad * 4);
#pragma unroll
  for (int cbo = 0; cbo < 4; ++cbo)
#pragma unroll
    for (int reg = 0; reg < 4; ++reg)
      Op[(obase + reg) * 64 + cbo * 16 + c] = fbf(oacc[cbo][reg]);
  if (c == 0) {
    const size_t lbase = (size_t)split * 32768 + (size_t)(b * 8 + hh) * 2048 + q0b + w * 16 + quad * 4;
#pragma unroll
    for (int reg = 0; reg < 4; ++reg) lsum[lbase + reg] = psum[reg];
  }
}

// -------------------- combine 4 split-K partials -> bf16 attn out [tok][h*64+dh] ------------
__global__ void attn_combine_kernel(const unsigned short* __restrict__ O0,
                                    const unsigned short* __restrict__ O1,
                                    const unsigned short* __restrict__ O2,
                                    const unsigned short* __restrict__ O3,
                                    const float* __restrict__ lsum,
                                    unsigned short* __restrict__ out) {
  int gr = blockIdx.x * 16 + (threadIdx.x >> 4);   // (b*8+h)*2048 + row, < 32768
  int d4 = (threadIdx.x & 15) * 4;
  float inv = 1.0f / (lsum[gr] + lsum[32768 + gr] + lsum[65536 + gr] + lsum[98304 + gr]);
  u16x4 p0 = *(const u16x4*)(O0 + (size_t)gr * 64 + d4);
  u16x4 p1 = *(const u16x4*)(O1 + (size_t)gr * 64 + d4);
  u16x4 p2 = *(const u16x4*)(O2 + (size_t)gr * 64 + d4);
  u16x4 p3 = *(const u16x4*)(O3 + (size_t)gr * 64 + d4);
  int bidx = gr >> 14, hidx = (gr >> 11) & 7, row = gr & 2047;
  u16x4 o;
#pragma unroll
  for (int u = 0; u < 4; ++u)
    o[u] = fbf((bf2f(p0[u]) + bf2f(p1[u]) + bf2f(p2[u]) + bf2f(p3[u])) * inv);
  *(u16x4*)(out + ((size_t)(bidx * 2048 + row) * 512) + hidx * 64 + d4) = o;
}

extern "C" void kernel_launch(void* const* d_in, const int* in_sizes, int n_in,
                              void* d_out, int out_size, void* d_ws, size_t ws_size,
                              hipStream_t stream) {
  const int*   ids      = (const int*)d_in[0];
  const float* embed    = (const float*)d_in[1];
  const float* Wq       = (const float*)d_in[2];
  const float* Wk       = (const float*)d_in[3];
  const float* Wv       = (const float*)d_in[4];
  const float* Wo       = (const float*)d_in[5];
  const float* rel_bias = (const float*)d_in[6];
  const float* wi0      = (const float*)d_in[7];
  const float* wi1      = (const float*)d_in[8];
  const float* wo_ffn   = (const float*)d_in[9];
  const float* ln0      = (const float*)d_in[10];
  const float* ln1      = (const float*)d_in[11];
  const float* final_ln = (const float*)d_in[12];
  float* out = (float*)d_out;
  char* wsb = (char*)d_ws;

  float*          x    = (float*)wsb;                              // 8 MB fp32
  unsigned short* h    = (unsigned short*)(wsb + 8388608);         // 4 MB bf16
  unsigned short* qb   = (unsigned short*)(wsb + 12582912);        // 4 MB
  unsigned short* kb   = (unsigned short*)(wsb + 16777216);        // 4 MB
  unsigned short* vt   = (unsigned short*)(wsb + 20971520);        // 4 MB
  unsigned short* wqT  = (unsigned short*)(wsb + 33554432);        // 2 MB
  unsigned short* wkT  = (unsigned short*)(wsb + 35651584);
  unsigned short* wvT  = (unsigned short*)(wsb + 37748736);
  unsigned short* woT  = (unsigned short*)(wsb + 39845888);
  unsigned short* wi0T = (unsigned short*)(wsb + 41943040);        // 4 MB
  unsigned short* wi1T = (unsigned short*)(wsb + 46137344);        // 4 MB
  unsigned short* wofT = (unsigned short*)(wsb + 50331648);        // 4 MB
  float*          dbias= (float*)(wsb + 54525952);                 // 128 KB
  unsigned short* t0b  = kb;    // 8 MB spanning kb+vt (dead during FFN)
  unsigned short* Op0  = h;                                        // h dead during attn
  unsigned short* Op1  = (unsigned short*)(wsb + 25165824);        // 4 MB
  unsigned short* Op2  = (unsigned short*)(wsb + 29360128);        // 4 MB
  unsigned short* Op3  = (unsigned short*)(wsb + 56623104);        // 4 MB
  float*          lsum = (float*)(wsb + 60817408);                 // 512 KB

  embed_kernel<<<NTOK, 128, 0, stream>>>(ids, embed, x);
  build_dbias_kernel<<<16, 256, 0, stream>>>(rel_bias, dbias);
  posbias_kernel<<<32768, 256, 0, stream>>>(dbias, out + 2097152);
  transw_kernel<<<dim3(16, 16, 16), 256, 0, stream>>>(Wq, Wk, Wv, Wo, wqT, wkT, wvT, woT, 512, 512);
  transw_kernel<<<dim3(32, 16, 8), 256, 0, stream>>>(wi0, wi1, wi0, wi0, wi0T, wi1T, wi0T, wi0T, 512, 1024);
  transw_kernel<<<dim3(16, 32, 4), 256, 0, stream>>>(wo_ffn, wo_ffn, wo_ffn, wo_ffn, wofT, wofT, wofT, wofT, 1024, 512);

  for (int l = 0; l < 4; ++l) {
    const unsigned short* wqT_l = wqT + (size_t)l * 262144;
    const unsigned short* wkT_l = wkT + (size_t)l * 262144;
    const unsigned short* wvT_l = wvT + (size_t)l * 262144;
    const unsigned short* woT_l = woT + (size_t)l * 262144;
    const unsigned short* wi0T_l = wi0T + (size_t)l * 524288;
    const unsigned short* wi1T_l = wi1T + (size_t)l * 524288;
    const unsigned short* wofT_l = wofT + (size_t)l * 524288;

    rmsnorm_bf16_kernel<<<NTOK, 128, 0, stream>>>(x, ln0 + l * 512, h);
    gemm128_kernel<<<dim3(8, 32, 3), 256, 0, stream>>>(h, wqT_l, wkT_l, wvT_l,
        qb, kb, vt, nullptr, NTOK, 512, 512, 0, 0, 1);
    attn_split_kernel<<<dim3(128, 8, 2), 256, 0, stream>>>(qb, kb, vt, dbias,
        Op0, Op1, Op2, Op3, lsum);
    attn_combine_kernel<<<2048, 256, 0, stream>>>(Op0, Op1, Op2, Op3, lsum, qb);
    gemm128_kernel<<<dim3(8, 32, 1), 256, 0, stream>>>(qb, woT_l, woT_l, woT_l,
        x, x, x, x, NTOK, 512, 512, 2, 2, 2);
    rmsnorm_bf16_kernel<<<NTOK, 128, 0, stream>>>(x, ln1 + l * 512, h);
    gemm_ffn_kernel<<<dim3(16, 32), 256, 0, stream>>>(h, wi0T_l, wi1T_l, t0b);
    gemm128_kernel<<<dim3(8, 32, 1), 256, 0, stream>>>(t0b, wofT_l, wofT_l, wofT_l,
        x, x, x, x, NTOK, 512, 1024, 2, 2, 2);
  }
  rmsnorm_f32_kernel<<<NTOK, 128, 0, stream>>>(x, final_ln, out);
}

// Round 5
// 664.556 us; speedup vs baseline: 1.1715x; 1.0317x over previous
//
#include <hip/hip_runtime.h>

#define NTOK 4096

typedef float f32x4 __attribute__((ext_vector_type(4)));
typedef short s16x8 __attribute__((ext_vector_type(8)));
typedef unsigned short u16x4 __attribute__((ext_vector_type(4)));
typedef unsigned short u16x8 __attribute__((ext_vector_type(8)));

__device__ __forceinline__ unsigned short fbf(float f) {
  unsigned int u = __float_as_uint(f);
  return (unsigned short)((u + 0x7FFFu + ((u >> 16) & 1u)) >> 16);
}
__device__ __forceinline__ float bf2f(unsigned short s) {
  return __uint_as_float(((unsigned int)s) << 16);
}
__device__ __forceinline__ float gelu_new_f(float x) {
  float inner = 0.7978845608028654f * (x + 0.044715f * x * x * x);
  return 0.5f * x * (1.0f + tanhf(inner));
}

// async global->LDS, 16B per lane. LDS dest = wave-uniform base + lane*16.
__device__ __forceinline__ void gl_lds16(const void* g, void* l) {
  __builtin_amdgcn_global_load_lds(
      (const __attribute__((address_space(1))) unsigned int*)g,
      (__attribute__((address_space(3))) unsigned int*)l, 16, 0, 0);
}

// -------------------- embedding gather (fp32 x) --------------------
__global__ void embed_kernel(const int* __restrict__ ids, const float* __restrict__ emb,
                             float* __restrict__ x) {
  int tok = blockIdx.x;
  int id = ids[tok];
  int t = threadIdx.x;
  *(float4*)(x + (size_t)tok * 512 + t * 4) = *(const float4*)(emb + (size_t)id * 512 + t * 4);
}

// -------------------- relative-position delta-bias table --------------------
__global__ void build_dbias_kernel(const float* __restrict__ rel_bias, float* __restrict__ dbias) {
  int d = blockIdx.x * 256 + threadIdx.x;
  if (d >= 4096) return;
  int rel = d - 2047;
  int bucket = (rel > 0) ? 16 : 0;
  int rp = rel < 0 ? -rel : rel;
  if (rp < 8) {
    bucket += rp;
  } else {
    float v = logf((float)rp / 8.0f) / logf(16.0f) * 8.0f;
    int rl = 8 + (int)v;
    bucket += (rl < 15) ? rl : 15;
  }
  for (int hh = 0; hh < 8; ++hh)
    dbias[hh * 4096 + d] = rel_bias[bucket * 8 + hh];
}

// -------------------- expand pos_bias output [1,H,S,S] --------------------
__global__ void posbias_kernel(const float* __restrict__ dbias, float* __restrict__ out1) {
  size_t g = (size_t)blockIdx.x * 256 + threadIdx.x;   // float4 index
  int k4 = (int)(g & 511) * 4;
  int qq = (int)((g >> 9) & 2047);
  int hh = (int)(g >> 20);
  const float* src = dbias + hh * 4096 + (k4 - qq + 2047);
  *(float4*)(out1 + g * 4) = make_float4(src[0], src[1], src[2], src[3]);
}

// -------------------- RMSNorm: fp32 in, bf16 out --------------------
__global__ void rmsnorm_bf16_kernel(const float* __restrict__ x, const float* __restrict__ w,
                                    unsigned short* __restrict__ out) {
  int tok = blockIdx.x;
  int t = threadIdx.x;  // 128
  float4 v = *(const float4*)(x + (size_t)tok * 512 + t * 4);
  float ss = v.x * v.x + v.y * v.y + v.z * v.z + v.w * v.w;
  for (int m = 1; m < 64; m <<= 1) ss += __shfl_xor(ss, m, 64);
  __shared__ float part[2];
  if ((t & 63) == 0) part[t >> 6] = ss;
  __syncthreads();
  float scale = rsqrtf((part[0] + part[1]) * (1.0f / 512.0f) + 1e-6f);
  float4 wv = *(const float4*)(w + t * 4);
  u16x4 o = {fbf(wv.x * v.x * scale), fbf(wv.y * v.y * scale),
             fbf(wv.z * v.z * scale), fbf(wv.w * v.w * scale)};
  *(u16x4*)(out + (size_t)tok * 512 + t * 4) = o;
}

// -------------------- RMSNorm: fp32 in, fp32 out (final) --------------------
__global__ void rmsnorm_f32_kernel(const float* __restrict__ x, const float* __restrict__ w,
                                   float* __restrict__ out) {
  int tok = blockIdx.x;
  int t = threadIdx.x;
  float4 v = *(const float4*)(x + (size_t)tok * 512 + t * 4);
  float ss = v.x * v.x + v.y * v.y + v.z * v.z + v.w * v.w;
  for (int m = 1; m < 64; m <<= 1) ss += __shfl_xor(ss, m, 64);
  __shared__ float part[2];
  if ((t & 63) == 0) part[t >> 6] = ss;
  __syncthreads();
  float scale = rsqrtf((part[0] + part[1]) * (1.0f / 512.0f) + 1e-6f);
  float4 wv = *(const float4*)(w + t * 4);
  *(float4*)(out + (size_t)tok * 512 + t * 4) =
      make_float4(wv.x * v.x * scale, wv.y * v.y * scale, wv.z * v.z * scale, wv.w * v.w * scale);
}

// -------------------- weight transpose+cast: src fp32 [R][C] -> dst bf16 [C][R] --------------------
__global__ void transw_kernel(const float* S0, const float* S1, const float* S2, const float* S3,
                              unsigned short* D0, unsigned short* D1, unsigned short* D2,
                              unsigned short* D3, int R, int C) {
  __shared__ float tile[32][33];
  int mat = blockIdx.z >> 2, layer = blockIdx.z & 3;
  const float* src = (mat == 0 ? S0 : mat == 1 ? S1 : mat == 2 ? S2 : S3) + (size_t)layer * R * C;
  unsigned short* dst = (mat == 0 ? D0 : mat == 1 ? D1 : mat == 2 ? D2 : D3) + (size_t)layer * R * C;
  int t = threadIdx.x;
  int r0 = blockIdx.y * 32, c0 = blockIdx.x * 32;
  int tr = t >> 3, tc = (t & 7) * 4;
  float4 v = *(const float4*)(src + (size_t)(r0 + tr) * C + c0 + tc);
  tile[tr][tc] = v.x; tile[tr][tc + 1] = v.y; tile[tr][tc + 2] = v.z; tile[tr][tc + 3] = v.w;
  __syncthreads();
  u16x4 o = {fbf(tile[tc + 0][tr]), fbf(tile[tc + 1][tr]),
             fbf(tile[tc + 2][tr]), fbf(tile[tc + 3][tr])};
  *(u16x4*)(dst + (size_t)(c0 + tr) * R + r0 + tc) = o;
}

// -------------------- bf16 MFMA GEMM: 64x64 tile, BK=64, global_load_lds dbuf ----
// mode 0: C bf16 [M][N]; mode 1: C bf16 transposed [N][M]; mode 2: C fp32 [M][N] = Res + acc
__global__ __launch_bounds__(256) void gemm64_kernel(
    const unsigned short* __restrict__ A,
    const unsigned short* B0, const unsigned short* B1, const unsigned short* B2,
    void* C0, void* C1, void* C2, const float* __restrict__ Res,
    int M, int N, int K, int m0, int m1, int m2) {
  __shared__ unsigned short As[2][64 * 64];
  __shared__ unsigned short Bs[2][64 * 64];
  const int z = blockIdx.z;
  const unsigned short* B = (z == 0) ? B0 : (z == 1) ? B1 : B2;
  void* Cptr = (z == 0) ? C0 : (z == 1) ? C1 : C2;
  const int mode = (z == 0) ? m0 : (z == 1) ? m1 : m2;
  const int t = threadIdx.x, lane = t & 63, w = t >> 6;
  const int quad = lane >> 4, c = lane & 15;
  const int wr = w >> 1, wc = w & 1;
  const int row0 = blockIdx.y * 64, col0 = blockIdx.x * 64;
  const int ar = t >> 3, aj = t & 7;
  const int asrc8 = (aj ^ (ar & 7)) * 8;
  const unsigned short* Agl = A + (size_t)(row0 + ar) * K + asrc8;
  const unsigned short* Bgl = B + (size_t)(col0 + ar) * K + asrc8;
  f32x4 acc[2][2];
#pragma unroll
  for (int i = 0; i < 2; ++i)
#pragma unroll
    for (int j = 0; j < 2; ++j) { f32x4 zz = {0.f, 0.f, 0.f, 0.f}; acc[i][j] = zz; }

  gl_lds16(Agl, &As[0][w * 512]);
  gl_lds16(Agl + 32 * (size_t)K, &As[0][2048 + w * 512]);
  gl_lds16(Bgl, &Bs[0][w * 512]);
  gl_lds16(Bgl + 32 * (size_t)K, &Bs[0][2048 + w * 512]);
  __syncthreads();

  int p = 0;
  for (int k0 = 0; k0 < K; k0 += 64) {
    if (k0 + 64 < K) {
      gl_lds16(Agl + k0 + 64, &As[p ^ 1][w * 512]);
      gl_lds16(Agl + k0 + 64 + 32 * (size_t)K, &As[p ^ 1][2048 + w * 512]);
      gl_lds16(Bgl + k0 + 64, &Bs[p ^ 1][w * 512]);
      gl_lds16(Bgl + k0 + 64 + 32 * (size_t)K, &Bs[p ^ 1][2048 + w * 512]);
    }
    s16x8 af[2][2], bf[2][2];
#pragma unroll
    for (int rb = 0; rb < 2; ++rb) {
      int r = wr * 32 + rb * 16 + c;
      int n = wc * 32 + rb * 16 + c;
#pragma unroll
      for (int ks = 0; ks < 2; ++ks) {
        af[rb][ks] = *(const s16x8*)&As[p][r * 64 + (((ks * 4 + quad) ^ (r & 7)) << 3)];
        bf[rb][ks] = *(const s16x8*)&Bs[p][n * 64 + (((ks * 4 + quad) ^ (n & 7)) << 3)];
      }
    }
#pragma unroll
    for (int rb = 0; rb < 2; ++rb)
#pragma unroll
      for (int cb = 0; cb < 2; ++cb)
#pragma unroll
        for (int ks = 0; ks < 2; ++ks)
          acc[rb][cb] = __builtin_amdgcn_mfma_f32_16x16x32_bf16(af[rb][ks], bf[cb][ks], acc[rb][cb], 0, 0, 0);
    __syncthreads();
    p ^= 1;
  }

  const int mb = row0 + wr * 32 + quad * 4;
  const int nb = col0 + wc * 32 + c;
  if (mode == 0) {
    unsigned short* Cp = (unsigned short*)Cptr;
#pragma unroll
    for (int rb = 0; rb < 2; ++rb)
#pragma unroll
      for (int cb = 0; cb < 2; ++cb) {
        size_t base = (size_t)(mb + rb * 16) * N + nb + cb * 16;
#pragma unroll
        for (int reg = 0; reg < 4; ++reg) Cp[base + (size_t)reg * N] = fbf(acc[rb][cb][reg]);
      }
  } else if (mode == 1) {
    unsigned short* Cp = (unsigned short*)Cptr;
#pragma unroll
    for (int rb = 0; rb < 2; ++rb)
#pragma unroll
      for (int cb = 0; cb < 2; ++cb) {
        u16x4 pk = {fbf(acc[rb][cb][0]), fbf(acc[rb][cb][1]), fbf(acc[rb][cb][2]), fbf(acc[rb][cb][3])};
        *(u16x4*)&Cp[(size_t)(nb + cb * 16) * M + mb + rb * 16] = pk;
      }
  } else {
    float* Cf = (float*)Cptr;
#pragma unroll
    for (int rb = 0; rb < 2; ++rb)
#pragma unroll
      for (int cb = 0; cb < 2; ++cb)
#pragma unroll
        for (int reg = 0; reg < 4; ++reg) {
          size_t o = (size_t)(mb + rb * 16 + reg) * N + nb + cb * 16;
          Cf[o] = Res[o] + acc[rb][cb][reg];
        }
  }
}

// -------------------- FFN-in GEMM (128x64, BK=64, global_load_lds dbuf) + fused gated GELU ----
__global__ __launch_bounds__(256) void gemm_ffn_kernel(
    const unsigned short* __restrict__ A, const unsigned short* __restrict__ B0g,
    const unsigned short* __restrict__ B1g, unsigned short* __restrict__ C) {
  __shared__ unsigned short As[2][128 * 64];
  __shared__ unsigned short Bs0[2][64 * 64];
  __shared__ unsigned short Bs1[2][64 * 64];
  const int t = threadIdx.x, lane = t & 63, w = t >> 6;
  const int quad = lane >> 4, c = lane & 15;
  const int wr = w >> 1, wc = w & 1;
  const int row0 = blockIdx.y * 128, col0 = blockIdx.x * 64;
  const int K = 512;
  f32x4 acc0[4][2], acc1[4][2];
#pragma unroll
  for (int i = 0; i < 4; ++i)
#pragma unroll
    for (int j = 0; j < 2; ++j) {
      f32x4 zz = {0.f, 0.f, 0.f, 0.f};
      acc0[i][j] = zz; acc1[i][j] = zz;
    }

  const int ar = t >> 3, aj = t & 7;
  const int asrc8 = (aj ^ (ar & 7)) * 8;
  const unsigned short* Agl = A + (size_t)(row0 + ar) * K + asrc8;
  const unsigned short* B0gl = B0g + (size_t)(col0 + ar) * K + asrc8;
  const unsigned short* B1gl = B1g + (size_t)(col0 + ar) * K + asrc8;

  auto stage = [&](int pp, int kk) {
    gl_lds16(Agl + kk, &As[pp][w * 512]);
    gl_lds16(Agl + kk + 32 * (size_t)K, &As[pp][2048 + w * 512]);
    gl_lds16(Agl + kk + 64 * (size_t)K, &As[pp][4096 + w * 512]);
    gl_lds16(Agl + kk + 96 * (size_t)K, &As[pp][6144 + w * 512]);
    gl_lds16(B0gl + kk, &Bs0[pp][w * 512]);
    gl_lds16(B0gl + kk + 32 * (size_t)K, &Bs0[pp][2048 + w * 512]);
    gl_lds16(B1gl + kk, &Bs1[pp][w * 512]);
    gl_lds16(B1gl + kk + 32 * (size_t)K, &Bs1[pp][2048 + w * 512]);
  };

  stage(0, 0);
  __syncthreads();

  int p = 0;
  for (int k0 = 0; k0 < K; k0 += 64) {
    if (k0 + 64 < K) stage(p ^ 1, k0 + 64);
    s16x8 af[4][2], bf0[2][2], bf1[2][2];
#pragma unroll
    for (int rb = 0; rb < 4; ++rb) {
      int r = wr * 64 + rb * 16 + c;
#pragma unroll
      for (int ks = 0; ks < 2; ++ks)
        af[rb][ks] = *(const s16x8*)&As[p][r * 64 + (((ks * 4 + quad) ^ (r & 7)) << 3)];
    }
#pragma unroll
    for (int cb = 0; cb < 2; ++cb) {
      int n = wc * 32 + cb * 16 + c;
#pragma unroll
      for (int ks = 0; ks < 2; ++ks) {
        bf0[cb][ks] = *(const s16x8*)&Bs0[p][n * 64 + (((ks * 4 + quad) ^ (n & 7)) << 3)];
        bf1[cb][ks] = *(const s16x8*)&Bs1[p][n * 64 + (((ks * 4 + quad) ^ (n & 7)) << 3)];
      }
    }
#pragma unroll
    for (int rb = 0; rb < 4; ++rb)
#pragma unroll
      for (int cb = 0; cb < 2; ++cb)
#pragma unroll
        for (int ks = 0; ks < 2; ++ks) {
          acc0[rb][cb] = __builtin_amdgcn_mfma_f32_16x16x32_bf16(af[rb][ks], bf0[cb][ks], acc0[rb][cb], 0, 0, 0);
          acc1[rb][cb] = __builtin_amdgcn_mfma_f32_16x16x32_bf16(af[rb][ks], bf1[cb][ks], acc1[rb][cb], 0, 0, 0);
        }
    __syncthreads();
    p ^= 1;
  }

  const int mb = row0 + wr * 64 + quad * 4;
  const int nb = col0 + wc * 32 + c;
#pragma unroll
  for (int rb = 0; rb < 4; ++rb)
#pragma unroll
    for (int cb = 0; cb < 2; ++cb) {
      size_t base = (size_t)(mb + rb * 16) * 1024 + nb + cb * 16;
#pragma unroll
      for (int reg = 0; reg < 4; ++reg)
        C[base + (size_t)reg * 1024] = fbf(gelu_new_f(acc0[rb][cb][reg]) * acc1[rb][cb][reg]);
    }
}

// -------------------- MFMA flash attention, split-K x2, no-max softmax, reg-prefetch --------
// grid (64, 8, 2): x = qtile(32) | split(2). Each block: 64 q-rows, 16 k-tiles of 64.
__global__ __launch_bounds__(256) void attn_split_kernel(
    const unsigned short* __restrict__ qg, const unsigned short* __restrict__ kg,
    const unsigned short* __restrict__ vtg, const float* __restrict__ dbias,
    unsigned short* __restrict__ Op0, unsigned short* __restrict__ Op1,
    float* __restrict__ lsum) {
  __shared__ unsigned short Ks[64 * 64];
  __shared__ unsigned short Vs[64 * 64];
  __shared__ unsigned short Ps[4][16 * 64];
  __shared__ float Bb[128];
  const int b = blockIdx.z, hh = blockIdx.y;
  const int q0b = (blockIdx.x & 31) * 64;
  const int split = blockIdx.x >> 5;             // 0 or 1
  unsigned short* Op = (split == 0) ? Op0 : Op1;
  const int t = threadIdx.x, lane = t & 63, w = t >> 6;
  const int quad = lane >> 4, c = lane & 15;
  const int hd = hh * 64;
  s16x8 qf[2];
#pragma unroll
  for (int ks = 0; ks < 2; ++ks)
    qf[ks] = *(const s16x8*)(qg + (size_t)(b * 2048 + q0b + w * 16 + c) * 512 + hd + ks * 32 + quad * 8);
  f32x4 oacc[4];
  float psum[4];
#pragma unroll
  for (int i = 0; i < 4; ++i) {
    f32x4 zz = {0.f, 0.f, 0.f, 0.f};
    oacc[i] = zz; psum[i] = 0.f;
  }
  const int biasbase = hh * 4096 + 2047 - q0b - 63;
  const int rowloc = w * 16 + quad * 4;
  const int srow = t >> 3, sjj = t & 7;          // staging coords (+32 for v=1)
  const unsigned short* kbase = kg + (size_t)(b * 2048) * 512 + hd;
  const unsigned short* vbase = vtg + (size_t)hd * 4096 + b * 2048;
  const int kt0 = split * 16;

  // prefetch first tile into registers
  s16x8 kpre[2], vpre[2];
  float bpre;
  {
    int k0 = kt0 * 64;
#pragma unroll
    for (int v = 0; v < 2; ++v) {
      int row = srow + 32 * v;
      kpre[v] = *(const s16x8*)(kbase + (size_t)(k0 + row) * 512 + sjj * 8);
      vpre[v] = *(const s16x8*)(vbase + (size_t)row * 4096 + k0 + sjj * 8);
    }
    bpre = dbias[biasbase + k0 + (t & 127)];
  }

  for (int kt = kt0; kt < kt0 + 16; ++kt) {
    __syncthreads();   // prior iter's LDS readers done
#pragma unroll
    for (int v = 0; v < 2; ++v) {
      int row = srow + 32 * v;
      int ch = (sjj ^ (row & 7)) << 3;
      *(s16x8*)&Ks[row * 64 + ch] = kpre[v];
      *(s16x8*)&Vs[row * 64 + ch] = vpre[v];
    }
    if (t < 128) Bb[t] = bpre;
    __syncthreads();
    // prefetch next tile during compute
    {
      int k0n = (kt + 1 < kt0 + 16) ? (kt + 1) * 64 : kt * 64;
#pragma unroll
      for (int v = 0; v < 2; ++v) {
        int row = srow + 32 * v;
        kpre[v] = *(const s16x8*)(kbase + (size_t)(k0n + row) * 512 + sjj * 8);
        vpre[v] = *(const s16x8*)(vbase + (size_t)row * 4096 + k0n + sjj * 8);
      }
      bpre = dbias[biasbase + k0n + (t & 127)];
    }

    f32x4 s[4];
#pragma unroll
    for (int i = 0; i < 4; ++i) { f32x4 zz = {0.f, 0.f, 0.f, 0.f}; s[i] = zz; }
#pragma unroll
    for (int ks = 0; ks < 2; ++ks)
#pragma unroll
      for (int cb = 0; cb < 4; ++cb) {
        int n = cb * 16 + c;
        s16x8 kf = *(const s16x8*)&Ks[n * 64 + (((ks * 4 + quad) ^ (n & 7)) << 3)];
        s[cb] = __builtin_amdgcn_mfma_f32_16x16x32_bf16(qf[ks], kf, s[cb], 0, 0, 0);
      }
#pragma unroll
    for (int cb = 0; cb < 4; ++cb) {
      int col = cb * 16 + c;
      int chunkbase = (col >> 3);
#pragma unroll
      for (int reg = 0; reg < 4; ++reg) {
        float pp = __expf(s[cb][reg] + Bb[col - rowloc - reg + 63]);
        psum[reg] += pp;
        int rowp = quad * 4 + reg;
        Ps[w][rowp * 64 + ((chunkbase ^ (rowp & 7)) << 3) + (col & 7)] = fbf(pp);
      }
    }
#pragma unroll
    for (int ks = 0; ks < 2; ++ks) {
      s16x8 pf = *(const s16x8*)&Ps[w][c * 64 + (((ks * 4 + quad) ^ (c & 7)) << 3)];
#pragma unroll
      for (int cbo = 0; cbo < 4; ++cbo) {
        int n = cbo * 16 + c;
        s16x8 vf = *(const s16x8*)&Vs[n * 64 + (((ks * 4 + quad) ^ (n & 7)) << 3)];
        oacc[cbo] = __builtin_amdgcn_mfma_f32_16x16x32_bf16(pf, vf, oacc[cbo], 0, 0, 0);
      }
    }
  }
#pragma unroll
  for (int reg = 0; reg < 4; ++reg) {
    float ps = psum[reg];
    ps += __shfl_xor(ps, 1, 64);
    ps += __shfl_xor(ps, 2, 64);
    ps += __shfl_xor(ps, 4, 64);
    ps += __shfl_xor(ps, 8, 64);
    psum[reg] = ps;
  }
  const size_t obase = ((size_t)(b * 8 + hh) * 2048 + q0b + w * 16 + quad * 4);
#pragma unroll
  for (int cbo = 0; cbo < 4; ++cbo)
#pragma unroll
    for (int reg = 0; reg < 4; ++reg)
      Op[(obase + reg) * 64 + cbo * 16 + c] = fbf(oacc[cbo][reg]);
  if (c == 0) {
    const size_t lbase = (size_t)split * 32768 + (size_t)(b * 8 + hh) * 2048 + q0b + w * 16 + quad * 4;
#pragma unroll
    for (int reg = 0; reg < 4; ++reg) lsum[lbase + reg] = psum[reg];
  }
}

// -------------------- combine 2 split-K partials -> bf16 attn out [tok][h*64+dh] ------------
__global__ void attn_combine_kernel(const unsigned short* __restrict__ O0,
                                    const unsigned short* __restrict__ O1,
                                    const float* __restrict__ lsum,
                                    unsigned short* __restrict__ out) {
  int gr = blockIdx.x * 16 + (threadIdx.x >> 4);   // (b*8+h)*2048 + row, < 32768
  int d4 = (threadIdx.x & 15) * 4;
  float inv = 1.0f / (lsum[gr] + lsum[32768 + gr]);
  u16x4 p0 = *(const u16x4*)(O0 + (size_t)gr * 64 + d4);
  u16x4 p1 = *(const u16x4*)(O1 + (size_t)gr * 64 + d4);
  int bidx = gr >> 14, hidx = (gr >> 11) & 7, row = gr & 2047;
  u16x4 o;
#pragma unroll
  for (int u = 0; u < 4; ++u)
    o[u] = fbf((bf2f(p0[u]) + bf2f(p1[u])) * inv);
  *(u16x4*)(out + ((size_t)(bidx * 2048 + row) * 512) + hidx * 64 + d4) = o;
}

extern "C" void kernel_launch(void* const* d_in, const int* in_sizes, int n_in,
                              void* d_out, int out_size, void* d_ws, size_t ws_size,
                              hipStream_t stream) {
  const int*   ids      = (const int*)d_in[0];
  const float* embed    = (const float*)d_in[1];
  const float* Wq       = (const float*)d_in[2];
  const float* Wk       = (const float*)d_in[3];
  const float* Wv       = (const float*)d_in[4];
  const float* Wo       = (const float*)d_in[5];
  const float* rel_bias = (const float*)d_in[6];
  const float* wi0      = (const float*)d_in[7];
  const float* wi1      = (const float*)d_in[8];
  const float* wo_ffn   = (const float*)d_in[9];
  const float* ln0      = (const float*)d_in[10];
  const float* ln1      = (const float*)d_in[11];
  const float* final_ln = (const float*)d_in[12];
  float* out = (float*)d_out;
  char* wsb = (char*)d_ws;

  float*          x    = (float*)wsb;                              // 8 MB fp32
  unsigned short* h    = (unsigned short*)(wsb + 8388608);         // 4 MB bf16
  unsigned short* qb   = (unsigned short*)(wsb + 12582912);        // 4 MB
  unsigned short* kb   = (unsigned short*)(wsb + 16777216);        // 4 MB
  unsigned short* vt   = (unsigned short*)(wsb + 20971520);        // 4 MB
  unsigned short* wqT  = (unsigned short*)(wsb + 33554432);        // 2 MB
  unsigned short* wkT  = (unsigned short*)(wsb + 35651584);
  unsigned short* wvT  = (unsigned short*)(wsb + 37748736);
  unsigned short* woT  = (unsigned short*)(wsb + 39845888);
  unsigned short* wi0T = (unsigned short*)(wsb + 41943040);        // 4 MB
  unsigned short* wi1T = (unsigned short*)(wsb + 46137344);        // 4 MB
  unsigned short* wofT = (unsigned short*)(wsb + 50331648);        // 4 MB
  float*          dbias= (float*)(wsb + 54525952);                 // 128 KB
  unsigned short* t0b  = kb;    // 8 MB spanning kb+vt (dead during FFN)
  unsigned short* Op0  = h;                                        // h dead during attn
  unsigned short* Op1  = (unsigned short*)(wsb + 25165824);        // 4 MB
  float*          lsum = (float*)(wsb + 60817408);                 // 256 KB used

  embed_kernel<<<NTOK, 128, 0, stream>>>(ids, embed, x);
  build_dbias_kernel<<<16, 256, 0, stream>>>(rel_bias, dbias);
  posbias_kernel<<<32768, 256, 0, stream>>>(dbias, out + 2097152);
  transw_kernel<<<dim3(16, 16, 16), 256, 0, stream>>>(Wq, Wk, Wv, Wo, wqT, wkT, wvT, woT, 512, 512);
  transw_kernel<<<dim3(32, 16, 8), 256, 0, stream>>>(wi0, wi1, wi0, wi0, wi0T, wi1T, wi0T, wi0T, 512, 1024);
  transw_kernel<<<dim3(16, 32, 4), 256, 0, stream>>>(wo_ffn, wo_ffn, wo_ffn, wo_ffn, wofT, wofT, wofT, wofT, 1024, 512);

  for (int l = 0; l < 4; ++l) {
    const unsigned short* wqT_l = wqT + (size_t)l * 262144;
    const unsigned short* wkT_l = wkT + (size_t)l * 262144;
    const unsigned short* wvT_l = wvT + (size_t)l * 262144;
    const unsigned short* woT_l = woT + (size_t)l * 262144;
    const unsigned short* wi0T_l = wi0T + (size_t)l * 524288;
    const unsigned short* wi1T_l = wi1T + (size_t)l * 524288;
    const unsigned short* wofT_l = wofT + (size_t)l * 524288;

    rmsnorm_bf16_kernel<<<NTOK, 128, 0, stream>>>(x, ln0 + l * 512, h);
    gemm64_kernel<<<dim3(8, 64, 3), 256, 0, stream>>>(h, wqT_l, wkT_l, wvT_l,
        qb, kb, vt, nullptr, NTOK, 512, 512, 0, 0, 1);
    attn_split_kernel<<<dim3(64, 8, 2), 256, 0, stream>>>(qb, kb, vt, dbias,
        Op0, Op1, lsum);
    attn_combine_kernel<<<2048, 256, 0, stream>>>(Op0, Op1, lsum, qb);
    gemm64_kernel<<<dim3(8, 64, 1), 256, 0, stream>>>(qb, woT_l, woT_l, woT_l,
        x, x, x, x, NTOK, 512, 512, 2, 2, 2);
    rmsnorm_bf16_kernel<<<NTOK, 128, 0, stream>>>(x, ln1 + l * 512, h);
    gemm_ffn_kernel<<<dim3(16, 32), 256, 0, stream>>>(h, wi0T_l, wi1T_l, t0b);
    gemm64_kernel<<<dim3(8, 64, 1), 256, 0, stream>>>(t0b, wofT_l, wofT_l, wofT_l,
        x, x, x, x, NTOK, 512, 1024, 2, 2, 2);
  }
  rmsnorm_f32_kernel<<<NTOK, 128, 0, stream>>>(x, final_ln, out);
}